// Round 5
// baseline (803.187 us; speedup 1.0000x reference)
//
#include <hip/hip_runtime.h>
#include <math.h>

#define NN   128
#define SS2  65           // float4 row stride (130 float2 / 2): even stride, 16B-aligned
                          // b128 everywhere; pass-0 lane word-stride 260 % 32 == 4 ->
                          // exactly 2 words/bank for 16-lane groups = conflict-free min
#define TT   512
#define NPIX 16384        // 128*128

__device__ __forceinline__ float2 cmul(float2 a, float2 w) {
    return make_float2(a.x * w.x - a.y * w.y, a.x * w.y + a.y * w.x);
}
__device__ __forceinline__ float2 cmulc(float2 a, float2 w) {   // a * conj(w)
    return make_float2(a.x * w.x + a.y * w.y, a.y * w.x - a.x * w.y);
}

// ---------- register FFT codelets (verified R2-R4) ----------
template<int SGN>
__device__ __forceinline__ void fft8(float2* f) {
    const float R = 0.70710678118654752f;
    const float WC[4] = {1.f, R, 0.f, -R};
    const float WS[4] = {0.f, R, 1.f, R};
    #pragma unroll
    for (int stage = 0; stage < 3; ++stage) {
        const int L = 8 >> stage, half = L >> 1, step = 1 << stage;
        #pragma unroll
        for (int base = 0; base < 8; base += L) {
            #pragma unroll
            for (int j = 0; j < half; ++j) {
                float2 u = f[base + j], v = f[base + half + j];
                f[base + j] = make_float2(u.x + v.x, u.y + v.y);
                float dx = u.x - v.x, dy = u.y - v.y;
                const int t = j * step;
                const float wr = WC[t];
                const float wi = (SGN > 0) ? WS[t] : -WS[t];
                f[base + half + j] = make_float2(dx * wr - dy * wi, dx * wi + dy * wr);
            }
        }
    }
    float2 tmp;
    tmp = f[1]; f[1] = f[4]; f[4] = tmp;
    tmp = f[3]; f[3] = f[6]; f[6] = tmp;
}

template<int SGN>
__device__ __forceinline__ void fft16(float2* f) {
    const float WC[8] = {1.f, 0.92387953251f, 0.70710678119f, 0.38268343236f,
                         0.f, -0.38268343236f, -0.70710678119f, -0.92387953251f};
    const float WS[8] = {0.f, 0.38268343236f, 0.70710678119f, 0.92387953251f,
                         1.f, 0.92387953251f, 0.70710678119f, 0.38268343236f};
    #pragma unroll
    for (int stage = 0; stage < 4; ++stage) {
        const int L = 16 >> stage, half = L >> 1, step = 1 << stage;
        #pragma unroll
        for (int base = 0; base < 16; base += L) {
            #pragma unroll
            for (int j = 0; j < half; ++j) {
                float2 u = f[base + j], v = f[base + half + j];
                f[base + j] = make_float2(u.x + v.x, u.y + v.y);
                float dx = u.x - v.x, dy = u.y - v.y;
                const int t = j * step;
                const float wr = WC[t];
                const float wi = (SGN > 0) ? WS[t] : -WS[t];
                f[base + half + j] = make_float2(dx * wr - dy * wi, dx * wi + dy * wr);
            }
        }
    }
    float2 tmp;
    tmp = f[1];  f[1]  = f[8];  f[8]  = tmp;
    tmp = f[2];  f[2]  = f[4];  f[4]  = tmp;
    tmp = f[3];  f[3]  = f[12]; f[12] = tmp;
    tmp = f[5];  f[5]  = f[10]; f[10] = tmp;
    tmp = f[7];  f[7]  = f[14]; f[14] = tmp;
    tmp = f[11]; f[11] = f[13]; f[13] = tmp;
}

__device__ __forceinline__ float waveReduceSum(float v) {
    #pragma unroll
    for (int off = 32; off > 0; off >>= 1) v += __shfl_down(v, off, 64);
    return v;
}

__device__ __forceinline__ void buildTw(float2* tw, int tid) {
    if (tid < 128) {
        float s, c;
        __sincosf((float)tid * 0.04908738521234052f, &s, &c);   // 2*pi/128
        tw[tid] = make_float2(c, s);
    }
}

// =======================================================================
// 2D FFT phases on F4 (float4-typed LDS, two adjacent float2 per slot).
// Per-axis layout: freq k = ka + 8*kb lives at position p = 16*ka + kb.
// Forward 1D: stepA fft8 over n1 per class t (+conj twiddle t*ka, store 16ka+t),
//             stepB fft16 over t per block ka (store 16ka+kb).
// Inverse 1D: stepA fft16 over kb per block ka (+twiddle t*ka, store 16ka+t),
//             stepB fft8 over ka per class t (store t+16nh).
// pass0 = row lines (elements adjacent), pass1 = column lines (column PAIRS
// packed in one float4).  All units read/write only their own cells ->
// one barrier between sweeps.
// =======================================================================

__device__ __forceinline__ void inv_p0A(float4* __restrict__ F4,
                                        const float2* __restrict__ tw, int tid) {
    #pragma unroll
    for (int i = 0; i < 2; ++i) {
        int u = i * TT + tid;
        int r = u & 127, ka = u >> 7;
        float4* M = F4 + r * SS2 + 8 * ka;
        float2 g[16];
        #pragma unroll
        for (int h = 0; h < 8; ++h) {
            float4 v = M[h];
            g[2*h] = make_float2(v.x, v.y); g[2*h+1] = make_float2(v.z, v.w);
        }
        fft16<1>(g);
        #pragma unroll
        for (int h = 0; h < 8; ++h) {
            float2 a = cmul(g[2*h],   tw[(2*h) * ka]);
            float2 c = cmul(g[2*h+1], tw[(2*h+1) * ka]);
            M[h] = make_float4(a.x, a.y, c.x, c.y);
        }
    }
}

__device__ __forceinline__ void inv_p0B(float4* __restrict__ F4, int tid) {
    #pragma unroll
    for (int i = 0; i < 2; ++i) {
        int u = i * TT + tid;
        int r = u & 127, tp = u >> 7;
        float4* M = F4 + r * SS2 + tp;
        float2 f0[8], f1[8];
        #pragma unroll
        for (int ka = 0; ka < 8; ++ka) {
            float4 v = M[8 * ka];
            f0[ka] = make_float2(v.x, v.y); f1[ka] = make_float2(v.z, v.w);
        }
        fft8<1>(f0); fft8<1>(f1);
        #pragma unroll
        for (int nh = 0; nh < 8; ++nh)
            M[8 * nh] = make_float4(f0[nh].x, f0[nh].y, f1[nh].x, f1[nh].y);
    }
}

__device__ __forceinline__ void inv_p1A(float4* __restrict__ F4,
                                        const float2* __restrict__ tw, int tid) {
    int ka = tid >> 6, cp = tid & 63;
    float4* M = F4 + 16 * ka * SS2 + cp;
    float2 g0[16], g1[16];
    #pragma unroll
    for (int kb = 0; kb < 16; ++kb) {
        float4 v = M[kb * SS2];
        g0[kb] = make_float2(v.x, v.y); g1[kb] = make_float2(v.z, v.w);
    }
    fft16<1>(g0); fft16<1>(g1);
    #pragma unroll
    for (int t = 0; t < 16; ++t) {
        float2 w = tw[t * ka];
        float2 a = cmul(g0[t], w), c = cmul(g1[t], w);
        M[t * SS2] = make_float4(a.x, a.y, c.x, c.y);
    }
}

// STORE=true: write u1 = |.|/16384 back (as packed (m,0)), acc += m (first order).
// STORE=false: acc += |.| only, NO LDS writes (second order).
template<bool STORE>
__device__ __forceinline__ void inv_p1B(float4* __restrict__ F4, int tid, float& acc) {
    #pragma unroll
    for (int i = 0; i < 2; ++i) {
        int u = i * TT + tid;
        int t = u >> 6, cp = u & 63;
        float2 f0[8], f1[8];
        #pragma unroll
        for (int ka = 0; ka < 8; ++ka) {
            float4 v = F4[(16 * ka + t) * SS2 + cp];
            f0[ka] = make_float2(v.x, v.y); f1[ka] = make_float2(v.z, v.w);
        }
        fft8<1>(f0); fft8<1>(f1);
        #pragma unroll
        for (int nh = 0; nh < 8; ++nh) {
            float m0 = sqrtf(f0[nh].x * f0[nh].x + f0[nh].y * f0[nh].y);
            float m1 = sqrtf(f1[nh].x * f1[nh].x + f1[nh].y * f1[nh].y);
            if (STORE) {
                m0 *= (1.f / 16384.f); m1 *= (1.f / 16384.f);
                acc += m0 + m1;
                F4[(t + 16 * nh) * SS2 + cp] = make_float4(m0, 0.f, m1, 0.f);
            } else {
                acc += m0 + m1;
            }
        }
    }
}

__device__ __forceinline__ void fwd_p0A(float4* __restrict__ F4,
                                        const float2* __restrict__ tw, int tid) {
    #pragma unroll
    for (int i = 0; i < 2; ++i) {
        int u = i * TT + tid;
        int r = u & 127, tp = u >> 7;
        float4* M = F4 + r * SS2 + tp;
        float2 f0[8], f1[8];
        #pragma unroll
        for (int n1 = 0; n1 < 8; ++n1) {
            float4 v = M[8 * n1];
            f0[n1] = make_float2(v.x, v.y); f1[n1] = make_float2(v.z, v.w);
        }
        fft8<-1>(f0); fft8<-1>(f1);
        #pragma unroll
        for (int ka = 0; ka < 8; ++ka) {
            float2 a = cmulc(f0[ka], tw[(2*tp) * ka]);
            float2 c = cmulc(f1[ka], tw[(2*tp+1) * ka]);
            M[8 * ka] = make_float4(a.x, a.y, c.x, c.y);
        }
    }
}

__device__ __forceinline__ void fwd_p0B(float4* __restrict__ F4, int tid) {
    #pragma unroll
    for (int i = 0; i < 2; ++i) {
        int u = i * TT + tid;
        int r = u & 127, ka = u >> 7;
        float4* M = F4 + r * SS2 + 8 * ka;
        float2 g[16];
        #pragma unroll
        for (int h = 0; h < 8; ++h) {
            float4 v = M[h];
            g[2*h] = make_float2(v.x, v.y); g[2*h+1] = make_float2(v.z, v.w);
        }
        fft16<-1>(g);
        #pragma unroll
        for (int h = 0; h < 8; ++h)
            M[h] = make_float4(g[2*h].x, g[2*h].y, g[2*h+1].x, g[2*h+1].y);
    }
}

__device__ __forceinline__ void fwd_p1A(float4* __restrict__ F4,
                                        const float2* __restrict__ tw, int tid) {
    #pragma unroll
    for (int i = 0; i < 2; ++i) {
        int u = i * TT + tid;
        int t = u >> 6, cp = u & 63;
        float2 f0[8], f1[8];
        #pragma unroll
        for (int n1 = 0; n1 < 8; ++n1) {
            float4 v = F4[(t + 16 * n1) * SS2 + cp];
            f0[n1] = make_float2(v.x, v.y); f1[n1] = make_float2(v.z, v.w);
        }
        fft8<-1>(f0); fft8<-1>(f1);
        #pragma unroll
        for (int ka = 0; ka < 8; ++ka) {
            float2 w = tw[t * ka];
            float2 a = cmulc(f0[ka], w), c = cmulc(f1[ka], w);
            F4[(16 * ka + t) * SS2 + cp] = make_float4(a.x, a.y, c.x, c.y);
        }
    }
}

// Final forward stage: u1_hat lands straight in registers (uh), never in LDS.
__device__ __forceinline__ void fwd_p1B(float4* __restrict__ F4, int tid,
                                        float2* __restrict__ uh) {
    int ka = tid >> 6, cp = tid & 63;
    float2 g0[16], g1[16];
    #pragma unroll
    for (int t = 0; t < 16; ++t) {
        float4 v = F4[(16 * ka + t) * SS2 + cp];
        g0[t] = make_float2(v.x, v.y); g1[t] = make_float2(v.z, v.w);
    }
    fft16<-1>(g0); fft16<-1>(g1);
    #pragma unroll
    for (int kb = 0; kb < 16; ++kb) { uh[2*kb] = g0[kb]; uh[2*kb+1] = g1[kb]; }
}

// ---------- K1: Morlet filter bank (permuted freq layout) + zero coeffs ----------
__global__ void k_psi(float* __restrict__ psi, float* __restrict__ coeffs) {
    int blk = blockIdx.x, tid = threadIdx.x;
    if (blk == 16) {
        for (int i = tid; i < 64 * 11; i += 256) coeffs[i] = 0.f;
        return;
    }
    int j = blk >> 2, l = blk & 3;
    float k0    = 2.35619449019234493f / (float)(1 << j);
    float sigma = 0.8f * (float)(1 << j);
    float s2    = sigma * sigma;
    float theta = 0.78539816339744831f * (float)l;
    float k0x = k0 * cosf(theta);
    float k0y = k0 * sinf(theta);
    float beta = expf(-0.5f * s2 * k0 * k0);
    const float FSTEP = 0.04908738521234052f;
    float* dst = psi + (size_t)blk * NPIX;
    for (int i = tid; i < NPIX; i += 256) {
        int pr = i >> 7, pc = i & 127;
        int kr = (pr >> 4) + 8 * (pr & 15);
        int kc = (pc >> 4) + 8 * (pc & 15);
        float fr = (float)(kr < 64 ? kr : kr - 128) * FSTEP;
        float fc = (float)(kc < 64 ? kc : kc - 128) * FSTEP;
        float dx = fr - k0x, dy = fc - k0y;
        float g1 = expf(-0.5f * s2 * (dx * dx + dy * dy));
        float g0 = expf(-0.5f * s2 * (fr * fr + fc * fc));
        dst[i] = g1 - beta * g0;
    }
}

// ---------- K2: i_hat = fft2(image) (permuted layout), s0 ----------
__global__ __attribute__((amdgpu_flat_work_group_size(TT, TT), amdgpu_waves_per_eu(2, 2)))
void k_ihat(const float* __restrict__ img,
            float2* __restrict__ ihat,
            float* __restrict__ coeffs) {
    __shared__ float4 F4[NN * SS2];
    __shared__ float2 tw[128];
    int tid = threadIdx.x, b = blockIdx.x;
    buildTw(tw, tid);
    const float* im = img + (size_t)b * NPIX;
    float acc = 0.f;
    #pragma unroll
    for (int k = 0; k < 16; ++k) {
        int e = k * 1024 + 2 * tid;
        float2 v = *(const float2*)(im + e);
        acc += v.x + v.y;
        F4[(e >> 7) * SS2 + ((e & 127) >> 1)] = make_float4(v.x, 0.f, v.y, 0.f);
    }
    float ws = waveReduceSum(acc);
    if ((tid & 63) == 0) atomicAdd(&coeffs[b * 11 + 0], ws * (1.f / 16384.f));
    __syncthreads();
    fwd_p0A(F4, tw, tid); __syncthreads();
    fwd_p0B(F4, tid);     __syncthreads();
    fwd_p1A(F4, tw, tid); __syncthreads();
    float2 uh[32];
    fwd_p1B(F4, tid, uh);
    int ka = tid >> 6, cp = tid & 63;
    float2* dst = ihat + (size_t)b * NPIX;
    #pragma unroll
    for (int kb = 0; kb < 16; ++kb) {
        *(float4*)(dst + (16 * ka + kb) * 128 + 2 * cp) =
            make_float4(uh[2*kb].x, uh[2*kb].y, uh[2*kb+1].x, uh[2*kb+1].y);
    }
}

// ---------- K3: fused first+second order scattering per (b, j1, l1) ----------
__global__ __attribute__((amdgpu_flat_work_group_size(TT, TT), amdgpu_waves_per_eu(2, 2)))
void k_scatter(const float2* __restrict__ ihat,
               const float* __restrict__ psi,
               float* __restrict__ coeffs) {
    __shared__ float4 F4[NN * SS2];
    __shared__ float2 tw[128];
    int tid = threadIdx.x;
    int x = blockIdx.x;
    int b = x & 63, l1 = (x >> 6) & 3, j1 = x >> 8;
    const float2* ih = ihat + (size_t)b * NPIX;
    const float*  p1 = psi + (size_t)(j1 * 4 + l1) * NPIX;
    buildTw(tw, tid);

    // product load: i_hat * psi_{j1,l1}
    #pragma unroll
    for (int k = 0; k < 16; ++k) {
        int e = k * 1024 + 2 * tid;
        float4 z = *(const float4*)(ih + e);        // two float2
        float2 p = *(const float2*)(p1 + e);
        F4[(e >> 7) * SS2 + ((e & 127) >> 1)] =
            make_float4(z.x * p.x, z.y * p.x, z.z * p.y, z.w * p.y);
    }
    __syncthreads();
    inv_p0A(F4, tw, tid); __syncthreads();
    inv_p0B(F4, tid);     __syncthreads();
    inv_p1A(F4, tw, tid); __syncthreads();
    float acc = 0.f;
    inv_p1B<true>(F4, tid, acc);               // u1 written, s1 partial in acc
    float ws1 = waveReduceSum(acc);
    if ((tid & 63) == 0) atomicAdd(&coeffs[b * 11 + 1 + j1], ws1 * (1.f / 65536.f));
    __syncthreads();

    int n2 = (3 - j1) * 4;
    if (n2 == 0) return;

    int ka = tid >> 6, cp = tid & 63;
    // prefetch psi2 for it=0 (hidden under the forward FFT)
    float2 pf[16];
    {
        const float* p2 = psi + (size_t)((j1 + 1) * 4) * NPIX;
        #pragma unroll
        for (int kb = 0; kb < 16; ++kb)
            pf[kb] = *(const float2*)(p2 + (16 * ka + kb) * 128 + 2 * cp);
    }
    fwd_p0A(F4, tw, tid); __syncthreads();
    fwd_p0B(F4, tid);     __syncthreads();
    fwd_p1A(F4, tw, tid); __syncthreads();
    float2 uh[32];
    fwd_p1B(F4, tid, uh);                      // u1_hat in registers only

    const float inv2 = 2.3283064365386963e-10f;   // 1/(16384*16*16384)
    for (int it = 0; it < n2; ++it) {
        int j2 = j1 + 1 + (it >> 2);
        int pair = (j1 == 0) ? (j2 - 1) : ((j1 == 1) ? (j2 + 1) : 5);
        __syncthreads();                       // prior reads of F4 complete
        #pragma unroll
        for (int kb = 0; kb < 16; ++kb) {
            float2 p = pf[kb];
            F4[(16 * ka + kb) * SS2 + cp] =
                make_float4(uh[2*kb].x * p.x, uh[2*kb].y * p.x,
                            uh[2*kb+1].x * p.y, uh[2*kb+1].y * p.y);
        }
        {   // prefetch next filter (in flight across the whole inverse FFT)
            int nit = (it + 1 < n2) ? it + 1 : it;
            const float* p2 = psi + (size_t)((j1 + 1 + (nit >> 2)) * 4 + (nit & 3)) * NPIX;
            #pragma unroll
            for (int kb = 0; kb < 16; ++kb)
                pf[kb] = *(const float2*)(p2 + (16 * ka + kb) * 128 + 2 * cp);
        }
        __syncthreads();
        inv_p0A(F4, tw, tid); __syncthreads();
        inv_p0B(F4, tid);     __syncthreads();
        inv_p1A(F4, tw, tid); __syncthreads();
        float a2 = 0.f;
        inv_p1B<false>(F4, tid, a2);           // mag-sum in registers, no writes
        float ws2 = waveReduceSum(a2);
        if ((tid & 63) == 0) atomicAdd(&coeffs[b * 11 + 5 + pair], ws2 * inv2);
    }
}

// ---------- K4: tiny MLP head ----------
__global__ void k_mlp(const float* __restrict__ coeffs,
                      const float* __restrict__ w1, const float* __restrict__ b1,
                      const float* __restrict__ w2, const float* __restrict__ b2,
                      float* __restrict__ out) {
    int b = threadIdx.x;
    if (b >= 64) return;
    float c[11];
    #pragma unroll
    for (int i = 0; i < 11; ++i) c[i] = coeffs[b * 11 + i];
    float h[4];
    #pragma unroll
    for (int k = 0; k < 4; ++k) {
        float s = b1[k];
        #pragma unroll
        for (int i = 0; i < 11; ++i) s += w1[k * 11 + i] * c[i];
        h[k] = fmaxf(s, 0.f);
    }
    #pragma unroll
    for (int o = 0; o < 10; ++o) {
        float s = b2[o];
        #pragma unroll
        for (int k = 0; k < 4; ++k) s += w2[o * 4 + k] * h[k];
        out[b * 10 + o] = 1.f / (1.f + expf(-s));
    }
}

extern "C" void kernel_launch(void* const* d_in, const int* in_sizes, int n_in,
                              void* d_out, int out_size, void* d_ws, size_t ws_size,
                              hipStream_t stream) {
    const float* img = (const float*)d_in[0];
    const float* w1  = (const float*)d_in[1];
    const float* b1  = (const float*)d_in[2];
    const float* w2  = (const float*)d_in[3];
    const float* b2  = (const float*)d_in[4];
    float* out = (float*)d_out;

    // workspace layout (floats): psi[16*16384] | ihat[64*16384 float2] | coeffs[64*11]
    float*  ws     = (float*)d_ws;
    float*  psi    = ws;
    float2* ihat   = (float2*)(ws + 16 * NPIX);
    float*  coeffs = ws + 16 * NPIX + 2 * 64 * NPIX;

    hipLaunchKernelGGL(k_psi,     dim3(17),   dim3(256), 0, stream, psi, coeffs);
    hipLaunchKernelGGL(k_ihat,    dim3(64),   dim3(TT),  0, stream, img, ihat, coeffs);
    hipLaunchKernelGGL(k_scatter, dim3(1024), dim3(TT),  0, stream, ihat, psi, coeffs);
    hipLaunchKernelGGL(k_mlp,     dim3(1),    dim3(64),  0, stream, coeffs, w1, b1, w2, b2, out);
}

// Round 6
// 473.798 us; speedup vs baseline: 1.6952x; 1.6952x over previous
//
#include <hip/hip_runtime.h>
#include <math.h>

#define NN   128
#define SS   129          // LDS row stride in float2 (ODD -> conflict-free lane stride)
#define TT   512          // R4-proven: 116 VGPR, no spill, 0 conflicts
#define NPIX 16384        // 128*128
#define EPT  32           // NPIX / TT

__device__ __forceinline__ float2 cmul(float2 a, float2 w) {
    return make_float2(a.x * w.x - a.y * w.y, a.x * w.y + a.y * w.x);
}
__device__ __forceinline__ float2 cmulc(float2 a, float2 w) {   // a * conj(w)
    return make_float2(a.x * w.x + a.y * w.y, a.y * w.x - a.x * w.y);
}

// ---------- register FFT codelets (verified R2-R4) ----------
template<int SGN>
__device__ __forceinline__ void fft8(float2* f) {
    const float R = 0.70710678118654752f;
    const float WC[4] = {1.f, R, 0.f, -R};
    const float WS[4] = {0.f, R, 1.f, R};
    #pragma unroll
    for (int stage = 0; stage < 3; ++stage) {
        const int L = 8 >> stage, half = L >> 1, step = 1 << stage;
        #pragma unroll
        for (int base = 0; base < 8; base += L) {
            #pragma unroll
            for (int j = 0; j < half; ++j) {
                float2 u = f[base + j], v = f[base + half + j];
                f[base + j] = make_float2(u.x + v.x, u.y + v.y);
                float dx = u.x - v.x, dy = u.y - v.y;
                const int t = j * step;
                const float wr = WC[t];
                const float wi = (SGN > 0) ? WS[t] : -WS[t];
                f[base + half + j] = make_float2(dx * wr - dy * wi, dx * wi + dy * wr);
            }
        }
    }
    float2 tmp;
    tmp = f[1]; f[1] = f[4]; f[4] = tmp;
    tmp = f[3]; f[3] = f[6]; f[6] = tmp;
}

template<int SGN>
__device__ __forceinline__ void fft16(float2* f) {
    const float WC[8] = {1.f, 0.92387953251f, 0.70710678119f, 0.38268343236f,
                         0.f, -0.38268343236f, -0.70710678119f, -0.92387953251f};
    const float WS[8] = {0.f, 0.38268343236f, 0.70710678119f, 0.92387953251f,
                         1.f, 0.92387953251f, 0.70710678119f, 0.38268343236f};
    #pragma unroll
    for (int stage = 0; stage < 4; ++stage) {
        const int L = 16 >> stage, half = L >> 1, step = 1 << stage;
        #pragma unroll
        for (int base = 0; base < 16; base += L) {
            #pragma unroll
            for (int j = 0; j < half; ++j) {
                float2 u = f[base + j], v = f[base + half + j];
                f[base + j] = make_float2(u.x + v.x, u.y + v.y);
                float dx = u.x - v.x, dy = u.y - v.y;
                const int t = j * step;
                const float wr = WC[t];
                const float wi = (SGN > 0) ? WS[t] : -WS[t];
                f[base + half + j] = make_float2(dx * wr - dy * wi, dx * wi + dy * wr);
            }
        }
    }
    float2 tmp;
    tmp = f[1];  f[1]  = f[8];  f[8]  = tmp;
    tmp = f[2];  f[2]  = f[4];  f[4]  = tmp;
    tmp = f[3];  f[3]  = f[12]; f[12] = tmp;
    tmp = f[5];  f[5]  = f[10]; f[10] = tmp;
    tmp = f[7];  f[7]  = f[14]; f[14] = tmp;
    tmp = f[11]; f[11] = f[13]; f[13] = tmp;
}

__device__ __forceinline__ float waveReduceSum(float v) {
    #pragma unroll
    for (int off = 32; off > 0; off >>= 1) v += __shfl_down(v, off, 64);
    return v;
}

__device__ __forceinline__ void buildTw(float2* tw, int tid) {
    if (tid < 128) {
        float s, c;
        __sincosf((float)tid * 0.04908738521234052f, &s, &c);   // 2*pi/128
        tw[tid] = make_float2(c, s);
    }
}

// =======================================================================
// 1D-FFT sweep phases on float2 LDS F, stride SS (R4-proven access patterns:
// lanes vary the line index x; row pass LS=SS (odd), col pass LS=1 -> 0
// bank conflicts).  Per-axis layout: freq k = ka+8*kb at position 16*ka+kb.
// Forward: stepA fft8 over n1 per class t (conj twiddle), stepB fft16 per ka.
// Inverse: stepA fft16 per ka (+twiddle), stepB fft8 per class t.
// Units touch only their own cells -> one barrier between sweeps.
// =======================================================================

template<int ES, int LS>
__device__ __forceinline__ void fwdA(float2* __restrict__ F,
                                     const float2* __restrict__ tw, int tid) {
    #pragma unroll
    for (int i = 0; i < 4; ++i) {
        int u = i * TT + tid;
        int t = u >> 7, x = u & 127;
        float2* M = F + x * LS;
        float2 f[8];
        #pragma unroll
        for (int n1 = 0; n1 < 8; ++n1) f[n1] = M[(t + 16 * n1) * ES];
        fft8<-1>(f);
        #pragma unroll
        for (int ka = 0; ka < 8; ++ka)
            M[(t + 16 * ka) * ES] = cmulc(f[ka], tw[t * ka]);
    }
}

template<int ES, int LS>
__device__ __forceinline__ void fwdB(float2* __restrict__ F, int tid) {
    #pragma unroll
    for (int i = 0; i < 2; ++i) {
        int u = i * TT + tid;
        int ka = u >> 7, x = u & 127;
        float2* M = F + x * LS;
        float2 g[16];
        #pragma unroll
        for (int t = 0; t < 16; ++t) g[t] = M[(16 * ka + t) * ES];
        fft16<-1>(g);
        #pragma unroll
        for (int kb = 0; kb < 16; ++kb) M[(16 * ka + kb) * ES] = g[kb];
    }
}

// Forward column stepB with u1_hat captured straight into registers (no LDS write).
__device__ __forceinline__ void fwdB_col_capture(const float2* __restrict__ F, int tid,
                                                 float2* __restrict__ uh) {
    #pragma unroll
    for (int i = 0; i < 2; ++i) {
        int u = i * TT + tid;
        int ka = u >> 7, c = u & 127;
        float2 g[16];
        #pragma unroll
        for (int t = 0; t < 16; ++t) g[t] = F[(16 * ka + t) * SS + c];
        fft16<-1>(g);
        #pragma unroll
        for (int kb = 0; kb < 16; ++kb) uh[i * 16 + kb] = g[kb];
    }
}

template<int ES, int LS>
__device__ __forceinline__ void invA(float2* __restrict__ F,
                                     const float2* __restrict__ tw, int tid) {
    #pragma unroll
    for (int i = 0; i < 2; ++i) {
        int u = i * TT + tid;
        int ka = u >> 7, x = u & 127;
        float2* M = F + x * LS;
        float2 g[16];
        #pragma unroll
        for (int kb = 0; kb < 16; ++kb) g[kb] = M[(16 * ka + kb) * ES];
        fft16<1>(g);
        #pragma unroll
        for (int t = 0; t < 16; ++t)
            M[(16 * ka + t) * ES] = cmul(g[t], tw[t * ka]);
    }
}

template<int ES, int LS>
__device__ __forceinline__ void invB(float2* __restrict__ F, int tid) {
    #pragma unroll
    for (int i = 0; i < 4; ++i) {
        int u = i * TT + tid;
        int t = u >> 7, x = u & 127;
        float2* M = F + x * LS;
        float2 f[8];
        #pragma unroll
        for (int ka = 0; ka < 8; ++ka) f[ka] = M[(16 * ka + t) * ES];
        fft8<1>(f);
        #pragma unroll
        for (int nh = 0; nh < 8; ++nh) M[(t + 16 * nh) * ES] = f[nh];
    }
}

// Inverse column stepB with fused magnitude.
// STORE=true: write u1=|.|/16384 back as (m,0) at spatial cells, acc += m.
// STORE=false: acc += |.| only, NO LDS writes (second order).
template<bool STORE>
__device__ __forceinline__ void invB_col_mag(float2* __restrict__ F, int tid, float& acc) {
    #pragma unroll
    for (int i = 0; i < 4; ++i) {
        int u = i * TT + tid;
        int t = u >> 7, c = u & 127;
        float2 f[8];
        #pragma unroll
        for (int ka = 0; ka < 8; ++ka) f[ka] = F[(16 * ka + t) * SS + c];
        fft8<1>(f);
        #pragma unroll
        for (int nh = 0; nh < 8; ++nh) {
            float m = sqrtf(f[nh].x * f[nh].x + f[nh].y * f[nh].y);
            if (STORE) {
                m *= (1.f / 16384.f);
                acc += m;
                F[(t + 16 * nh) * SS + c] = make_float2(m, 0.f);
            } else {
                acc += m;
            }
        }
    }
}

// ---------- K1: Morlet filter bank (permuted freq layout) + zero coeffs ----------
__global__ void k_psi(float* __restrict__ psi, float* __restrict__ coeffs) {
    int blk = blockIdx.x, tid = threadIdx.x;
    if (blk == 16) {
        for (int i = tid; i < 64 * 11; i += 256) coeffs[i] = 0.f;
        return;
    }
    int j = blk >> 2, l = blk & 3;
    float k0    = 2.35619449019234493f / (float)(1 << j);
    float sigma = 0.8f * (float)(1 << j);
    float s2    = sigma * sigma;
    float theta = 0.78539816339744831f * (float)l;
    float k0x = k0 * cosf(theta);
    float k0y = k0 * sinf(theta);
    float beta = expf(-0.5f * s2 * k0 * k0);
    const float FSTEP = 0.04908738521234052f;
    float* dst = psi + (size_t)blk * NPIX;
    for (int i = tid; i < NPIX; i += 256) {
        int pr = i >> 7, pc = i & 127;
        int kr = (pr >> 4) + 8 * (pr & 15);
        int kc = (pc >> 4) + 8 * (pc & 15);
        float fr = (float)(kr < 64 ? kr : kr - 128) * FSTEP;
        float fc = (float)(kc < 64 ? kc : kc - 128) * FSTEP;
        float dx = fr - k0x, dy = fc - k0y;
        float g1 = expf(-0.5f * s2 * (dx * dx + dy * dy));
        float g0 = expf(-0.5f * s2 * (fr * fr + fc * fc));
        dst[i] = g1 - beta * g0;
    }
}

// ---------- K2: i_hat = fft2(image) (permuted layout), s0 ----------
__global__ __attribute__((amdgpu_flat_work_group_size(TT, TT), amdgpu_waves_per_eu(2, 2)))
void k_ihat(const float* __restrict__ img,
            float2* __restrict__ ihat,
            float* __restrict__ coeffs) {
    __shared__ float2 F[NN * SS];
    __shared__ float2 tw[128];
    int tid = threadIdx.x, b = blockIdx.x;
    buildTw(tw, tid);
    const float* im = img + (size_t)b * NPIX;
    float acc = 0.f;
    #pragma unroll
    for (int k = 0; k < EPT; ++k) {
        int e = k * TT + tid;
        float v = im[e];
        acc += v;
        F[(e >> 7) * SS + (e & 127)] = make_float2(v, 0.f);
    }
    float ws = waveReduceSum(acc);
    if ((tid & 63) == 0) atomicAdd(&coeffs[b * 11 + 0], ws * (1.f / 16384.f));
    __syncthreads();
    fwdA<1, SS>(F, tw, tid);  __syncthreads();   // rows
    fwdB<1, SS>(F, tid);      __syncthreads();
    fwdA<SS, 1>(F, tw, tid);  __syncthreads();   // cols
    float2 uh[32];
    fwdB_col_capture(F, tid, uh);
    float2* dst = ihat + (size_t)b * NPIX;
    #pragma unroll
    for (int i = 0; i < 2; ++i) {
        int u = i * TT + tid;
        int ka = u >> 7, c = u & 127;
        #pragma unroll
        for (int kb = 0; kb < 16; ++kb)
            dst[(16 * ka + kb) * NN + c] = uh[i * 16 + kb];
    }
}

// ---------- K3: fused first+second order scattering per (b, j1, l1) ----------
__global__ __attribute__((amdgpu_flat_work_group_size(TT, TT), amdgpu_waves_per_eu(2, 2)))
void k_scatter(const float2* __restrict__ ihat,
               const float* __restrict__ psi,
               float* __restrict__ coeffs) {
    __shared__ float2 F[NN * SS];
    __shared__ float2 tw[128];
    int tid = threadIdx.x;
    int x = blockIdx.x;
    int b = x & 63, l1 = (x >> 6) & 3, j1 = x >> 8;
    const float2* ih = ihat + (size_t)b * NPIX;
    const float*  p1 = psi + (size_t)(j1 * 4 + l1) * NPIX;
    buildTw(tw, tid);

    // product load: i_hat * psi_{j1,l1} (both permuted freq layout)
    #pragma unroll
    for (int k = 0; k < EPT; ++k) {
        int e = k * TT + tid;
        float2 z = ih[e];
        float  p = p1[e];
        F[(e >> 7) * SS + (e & 127)] = make_float2(z.x * p, z.y * p);
    }
    __syncthreads();
    invA<1, SS>(F, tw, tid);  __syncthreads();   // rows
    invB<1, SS>(F, tid);      __syncthreads();
    invA<SS, 1>(F, tw, tid);  __syncthreads();   // cols
    float acc = 0.f;
    invB_col_mag<true>(F, tid, acc);             // u1 written at spatial cells
    float ws1 = waveReduceSum(acc);
    if ((tid & 63) == 0) atomicAdd(&coeffs[b * 11 + 1 + j1], ws1 * (1.f / 65536.f));

    int n2 = (3 - j1) * 4;
    if (n2 == 0) return;                         // j1=3: first order only

    __syncthreads();                             // u1 writes visible
    fwdA<1, SS>(F, tw, tid);  __syncthreads();   // rows
    fwdB<1, SS>(F, tid);      __syncthreads();
    fwdA<SS, 1>(F, tw, tid);  __syncthreads();   // cols
    float2 uh[32];
    fwdB_col_capture(F, tid, uh);                // u1_hat in registers only
    // No barrier needed: the product below writes exactly the cells this
    // thread just read (same (ka,c) unit mapping).

    const float inv2 = 2.3283064365386963e-10f;  // 1/(16384*16*16384) = 2^-32
    for (int it = 0; it < n2; ++it) {
        int j2 = j1 + 1 + (it >> 2);
        int pair = (j1 == 0) ? (j2 - 1) : ((j1 == 1) ? (j2 + 1) : 5);
        const float* p2 = psi + (size_t)(j2 * 4 + (it & 3)) * NPIX;
        #pragma unroll
        for (int i = 0; i < 2; ++i) {
            int u = i * TT + tid;
            int ka = u >> 7, c = u & 127;
            #pragma unroll
            for (int kb = 0; kb < 16; ++kb) {
                float p = p2[(16 * ka + kb) * NN + c];
                float2 z = uh[i * 16 + kb];
                F[(16 * ka + kb) * SS + c] = make_float2(z.x * p, z.y * p);
            }
        }
        __syncthreads();
        invA<1, SS>(F, tw, tid);  __syncthreads();
        invB<1, SS>(F, tid);      __syncthreads();
        invA<SS, 1>(F, tw, tid);  __syncthreads();
        float a2 = 0.f;
        invB_col_mag<false>(F, tid, a2);         // register-only mag sum
        float ws2 = waveReduceSum(a2);
        if ((tid & 63) == 0) atomicAdd(&coeffs[b * 11 + 5 + pair], ws2 * inv2);
        __syncthreads();                         // all reads done before next product
    }
}

// ---------- K4: tiny MLP head ----------
__global__ void k_mlp(const float* __restrict__ coeffs,
                      const float* __restrict__ w1, const float* __restrict__ b1,
                      const float* __restrict__ w2, const float* __restrict__ b2,
                      float* __restrict__ out) {
    int b = threadIdx.x;
    if (b >= 64) return;
    float c[11];
    #pragma unroll
    for (int i = 0; i < 11; ++i) c[i] = coeffs[b * 11 + i];
    float h[4];
    #pragma unroll
    for (int k = 0; k < 4; ++k) {
        float s = b1[k];
        #pragma unroll
        for (int i = 0; i < 11; ++i) s += w1[k * 11 + i] * c[i];
        h[k] = fmaxf(s, 0.f);
    }
    #pragma unroll
    for (int o = 0; o < 10; ++o) {
        float s = b2[o];
        #pragma unroll
        for (int k = 0; k < 4; ++k) s += w2[o * 4 + k] * h[k];
        out[b * 10 + o] = 1.f / (1.f + expf(-s));
    }
}

extern "C" void kernel_launch(void* const* d_in, const int* in_sizes, int n_in,
                              void* d_out, int out_size, void* d_ws, size_t ws_size,
                              hipStream_t stream) {
    const float* img = (const float*)d_in[0];
    const float* w1  = (const float*)d_in[1];
    const float* b1  = (const float*)d_in[2];
    const float* w2  = (const float*)d_in[3];
    const float* b2  = (const float*)d_in[4];
    float* out = (float*)d_out;

    // workspace layout (floats): psi[16*16384] | ihat[64*16384 float2] | coeffs[64*11]
    float*  ws     = (float*)d_ws;
    float*  psi    = ws;
    float2* ihat   = (float2*)(ws + 16 * NPIX);
    float*  coeffs = ws + 16 * NPIX + 2 * 64 * NPIX;

    hipLaunchKernelGGL(k_psi,     dim3(17),   dim3(256), 0, stream, psi, coeffs);
    hipLaunchKernelGGL(k_ihat,    dim3(64),   dim3(TT),  0, stream, img, ihat, coeffs);
    hipLaunchKernelGGL(k_scatter, dim3(1024), dim3(TT),  0, stream, ihat, psi, coeffs);
    hipLaunchKernelGGL(k_mlp,     dim3(1),    dim3(64),  0, stream, coeffs, w1, b1, w2, b2, out);
}

// Round 7
// 442.195 us; speedup vs baseline: 1.8164x; 1.0715x over previous
//
#include <hip/hip_runtime.h>
#include <math.h>

#define NN   128
#define SS   129          // LDS row stride in float2 (ODD -> conflict-free lane stride)
#define TT   512          // R4/R6-proven: ~128 VGPR, no spill, 0 conflicts
#define NPIX 16384        // 128*128
#define EPT  32           // NPIX / TT

__device__ __forceinline__ float2 cmul(float2 a, float2 w) {
    return make_float2(a.x * w.x - a.y * w.y, a.x * w.y + a.y * w.x);
}
__device__ __forceinline__ float2 cmulc(float2 a, float2 w) {   // a * conj(w)
    return make_float2(a.x * w.x + a.y * w.y, a.y * w.x - a.x * w.y);
}

// ---------- register FFT codelets (verified R2-R6) ----------
template<int SGN>
__device__ __forceinline__ void fft8(float2* f) {
    const float R = 0.70710678118654752f;
    const float WC[4] = {1.f, R, 0.f, -R};
    const float WS[4] = {0.f, R, 1.f, R};
    #pragma unroll
    for (int stage = 0; stage < 3; ++stage) {
        const int L = 8 >> stage, half = L >> 1, step = 1 << stage;
        #pragma unroll
        for (int base = 0; base < 8; base += L) {
            #pragma unroll
            for (int j = 0; j < half; ++j) {
                float2 u = f[base + j], v = f[base + half + j];
                f[base + j] = make_float2(u.x + v.x, u.y + v.y);
                float dx = u.x - v.x, dy = u.y - v.y;
                const int t = j * step;
                const float wr = WC[t];
                const float wi = (SGN > 0) ? WS[t] : -WS[t];
                f[base + half + j] = make_float2(dx * wr - dy * wi, dx * wi + dy * wr);
            }
        }
    }
    float2 tmp;
    tmp = f[1]; f[1] = f[4]; f[4] = tmp;
    tmp = f[3]; f[3] = f[6]; f[6] = tmp;
}

template<int SGN>
__device__ __forceinline__ void fft16(float2* f) {
    const float WC[8] = {1.f, 0.92387953251f, 0.70710678119f, 0.38268343236f,
                         0.f, -0.38268343236f, -0.70710678119f, -0.92387953251f};
    const float WS[8] = {0.f, 0.38268343236f, 0.70710678119f, 0.92387953251f,
                         1.f, 0.92387953251f, 0.70710678119f, 0.38268343236f};
    #pragma unroll
    for (int stage = 0; stage < 4; ++stage) {
        const int L = 16 >> stage, half = L >> 1, step = 1 << stage;
        #pragma unroll
        for (int base = 0; base < 16; base += L) {
            #pragma unroll
            for (int j = 0; j < half; ++j) {
                float2 u = f[base + j], v = f[base + half + j];
                f[base + j] = make_float2(u.x + v.x, u.y + v.y);
                float dx = u.x - v.x, dy = u.y - v.y;
                const int t = j * step;
                const float wr = WC[t];
                const float wi = (SGN > 0) ? WS[t] : -WS[t];
                f[base + half + j] = make_float2(dx * wr - dy * wi, dx * wi + dy * wr);
            }
        }
    }
    float2 tmp;
    tmp = f[1];  f[1]  = f[8];  f[8]  = tmp;
    tmp = f[2];  f[2]  = f[4];  f[4]  = tmp;
    tmp = f[3];  f[3]  = f[12]; f[12] = tmp;
    tmp = f[5];  f[5]  = f[10]; f[10] = tmp;
    tmp = f[7];  f[7]  = f[14]; f[14] = tmp;
    tmp = f[11]; f[11] = f[13]; f[13] = tmp;
}

__device__ __forceinline__ float waveReduceSum(float v) {
    #pragma unroll
    for (int off = 32; off > 0; off >>= 1) v += __shfl_down(v, off, 64);
    return v;
}

__device__ __forceinline__ void buildTw(float2* tw, int tid) {
    if (tid < 128) {
        float s, c;
        __sincosf((float)tid * 0.04908738521234052f, &s, &c);   // 2*pi/128
        tw[tid] = make_float2(c, s);
    }
}

// =======================================================================
// Sweep phases (R6-proven conflict-free lane mappings).
// Per-axis layout: freq k = ka+8*kb stored at position p = 16*ka+kb.
// Forward 1D: stepA fft8 over n1 per class t (conj twiddle), stepB fft16 per ka.
// Inverse 1D: stepA fft16 over kb per ka (+twiddle), stepB fft8 per class t.
// 2D inverse runs COLUMN pass first (stepA consumed from registers), then rows.
// =======================================================================

template<int ES, int LS>
__device__ __forceinline__ void fwdA(float2* __restrict__ F,
                                     const float2* __restrict__ tw, int tid) {
    #pragma unroll
    for (int i = 0; i < 4; ++i) {
        int u = i * TT + tid;
        int t = u >> 7, x = u & 127;
        float2* M = F + x * LS;
        float2 f[8];
        #pragma unroll
        for (int n1 = 0; n1 < 8; ++n1) f[n1] = M[(t + 16 * n1) * ES];
        fft8<-1>(f);
        #pragma unroll
        for (int ka = 0; ka < 8; ++ka)
            M[(t + 16 * ka) * ES] = cmulc(f[ka], tw[t * ka]);
    }
}

template<int ES, int LS>
__device__ __forceinline__ void fwdB(float2* __restrict__ F, int tid) {
    #pragma unroll
    for (int i = 0; i < 2; ++i) {
        int u = i * TT + tid;
        int ka = u >> 7, x = u & 127;
        float2* M = F + x * LS;
        float2 g[16];
        #pragma unroll
        for (int t = 0; t < 16; ++t) g[t] = M[(16 * ka + t) * ES];
        fft16<-1>(g);
        #pragma unroll
        for (int kb = 0; kb < 16; ++kb) M[(16 * ka + kb) * ES] = g[kb];
    }
}

// Forward column stepB with u1_hat captured straight into registers (no LDS write).
// Unit (ka, c) holds freq cells (16*ka+kb, c) -- exactly what the inverse column
// stepA needs, enabling the register-resident product next round.
__device__ __forceinline__ void fwdB_col_capture(const float2* __restrict__ F, int tid,
                                                 float2* __restrict__ uh) {
    #pragma unroll
    for (int i = 0; i < 2; ++i) {
        int u = i * TT + tid;
        int ka = u >> 7, c = u & 127;
        float2 g[16];
        #pragma unroll
        for (int t = 0; t < 16; ++t) g[t] = F[(16 * ka + t) * SS + c];
        fft16<-1>(g);
        #pragma unroll
        for (int kb = 0; kb < 16; ++kb) uh[i * 16 + kb] = g[kb];
    }
}

template<int ES, int LS>
__device__ __forceinline__ void invA(float2* __restrict__ F,
                                     const float2* __restrict__ tw, int tid) {
    #pragma unroll
    for (int i = 0; i < 2; ++i) {
        int u = i * TT + tid;
        int ka = u >> 7, x = u & 127;
        float2* M = F + x * LS;
        float2 g[16];
        #pragma unroll
        for (int kb = 0; kb < 16; ++kb) g[kb] = M[(16 * ka + kb) * ES];
        fft16<1>(g);
        #pragma unroll
        for (int t = 0; t < 16; ++t)
            M[(16 * ka + t) * ES] = cmul(g[t], tw[t * ka]);
    }
}

template<int ES, int LS>
__device__ __forceinline__ void invB(float2* __restrict__ F, int tid) {
    #pragma unroll
    for (int i = 0; i < 4; ++i) {
        int u = i * TT + tid;
        int t = u >> 7, x = u & 127;
        float2* M = F + x * LS;
        float2 f[8];
        #pragma unroll
        for (int ka = 0; ka < 8; ++ka) f[ka] = M[(16 * ka + t) * ES];
        fft8<1>(f);
        #pragma unroll
        for (int nh = 0; nh < 8; ++nh) M[(t + 16 * nh) * ES] = f[nh];
    }
}

// Inverse stepB with fused magnitude (generic axis).
// STORE=true: write u1=|.|/16384 back as (m,0) at spatial cells, acc += m.
// STORE=false: acc += |.| only, NO LDS writes.
template<int ES, int LS, bool STORE>
__device__ __forceinline__ void invB_mag(float2* __restrict__ F, int tid, float& acc) {
    #pragma unroll
    for (int i = 0; i < 4; ++i) {
        int u = i * TT + tid;
        int t = u >> 7, x = u & 127;
        float2* M = F + x * LS;
        float2 f[8];
        #pragma unroll
        for (int ka = 0; ka < 8; ++ka) f[ka] = M[(16 * ka + t) * ES];
        fft8<1>(f);
        #pragma unroll
        for (int nh = 0; nh < 8; ++nh) {
            float m = sqrtf(f[nh].x * f[nh].x + f[nh].y * f[nh].y);
            if (STORE) {
                m *= (1.f / 16384.f);
                acc += m;
                M[(t + 16 * nh) * ES] = make_float2(m, 0.f);
            } else {
                acc += m;
            }
        }
    }
}

// ---------- K1: Morlet filter bank (permuted freq layout) + zero coeffs ----------
__global__ void k_psi(float* __restrict__ psi, float* __restrict__ coeffs) {
    int blk = blockIdx.x, tid = threadIdx.x;
    if (blk == 16) {
        for (int i = tid; i < 64 * 11; i += 256) coeffs[i] = 0.f;
        return;
    }
    int j = blk >> 2, l = blk & 3;
    float k0    = 2.35619449019234493f / (float)(1 << j);
    float sigma = 0.8f * (float)(1 << j);
    float s2    = sigma * sigma;
    float theta = 0.78539816339744831f * (float)l;
    float k0x = k0 * cosf(theta);
    float k0y = k0 * sinf(theta);
    float beta = expf(-0.5f * s2 * k0 * k0);
    const float FSTEP = 0.04908738521234052f;
    float* dst = psi + (size_t)blk * NPIX;
    for (int i = tid; i < NPIX; i += 256) {
        int pr = i >> 7, pc = i & 127;
        int kr = (pr >> 4) + 8 * (pr & 15);
        int kc = (pc >> 4) + 8 * (pc & 15);
        float fr = (float)(kr < 64 ? kr : kr - 128) * FSTEP;
        float fc = (float)(kc < 64 ? kc : kc - 128) * FSTEP;
        float dx = fr - k0x, dy = fc - k0y;
        float g1 = expf(-0.5f * s2 * (dx * dx + dy * dy));
        float g0 = expf(-0.5f * s2 * (fr * fr + fc * fc));
        dst[i] = g1 - beta * g0;
    }
}

// ---------- K2: i_hat = fft2(image) (permuted layout), s0 ----------
__global__ __attribute__((amdgpu_flat_work_group_size(TT, TT), amdgpu_waves_per_eu(2, 2)))
void k_ihat(const float* __restrict__ img,
            float2* __restrict__ ihat,
            float* __restrict__ coeffs) {
    __shared__ float2 F[NN * SS];
    __shared__ float2 tw[128];
    int tid = threadIdx.x, b = blockIdx.x;
    buildTw(tw, tid);
    const float* im = img + (size_t)b * NPIX;
    float acc = 0.f;
    #pragma unroll
    for (int k = 0; k < EPT; ++k) {
        int e = k * TT + tid;
        float v = im[e];
        acc += v;
        F[(e >> 7) * SS + (e & 127)] = make_float2(v, 0.f);
    }
    float ws = waveReduceSum(acc);
    if ((tid & 63) == 0) atomicAdd(&coeffs[b * 11 + 0], ws * (1.f / 16384.f));
    __syncthreads();
    fwdA<1, SS>(F, tw, tid);  __syncthreads();   // rows
    fwdB<1, SS>(F, tid);      __syncthreads();
    fwdA<SS, 1>(F, tw, tid);  __syncthreads();   // cols
    float2 uh[32];
    fwdB_col_capture(F, tid, uh);
    float2* dst = ihat + (size_t)b * NPIX;
    #pragma unroll
    for (int i = 0; i < 2; ++i) {
        int u = i * TT + tid;
        int ka = u >> 7, c = u & 127;
        #pragma unroll
        for (int kb = 0; kb < 16; ++kb)
            dst[(16 * ka + kb) * NN + c] = uh[i * 16 + kb];
    }
}

// ---------- K3: fused first+second order scattering per (b, j1, l1) ----------
__global__ __attribute__((amdgpu_flat_work_group_size(TT, TT), amdgpu_waves_per_eu(2, 2)))
void k_scatter(const float2* __restrict__ ihat,
               const float* __restrict__ psi,
               float* __restrict__ coeffs) {
    __shared__ float2 F[NN * SS];
    __shared__ float2 tw[128];
    int tid = threadIdx.x;
    int x = blockIdx.x;
    int b = x & 63, l1 = (x >> 6) & 3, j1 = x >> 8;
    const float2* ih = ihat + (size_t)b * NPIX;
    const float*  p1 = psi + (size_t)(j1 * 4 + l1) * NPIX;
    buildTw(tw, tid);

    // ---- first inverse, COLUMN pass stepA from the global product (registers) ----
    #pragma unroll
    for (int i = 0; i < 2; ++i) {
        int u = i * TT + tid;
        int ka = u >> 7, c = u & 127;
        float2 g[16];
        #pragma unroll
        for (int kb = 0; kb < 16; ++kb) {
            int e = (16 * ka + kb) * NN + c;
            float2 z = ih[e];
            float  p = p1[e];
            g[kb] = make_float2(z.x * p, z.y * p);
        }
        fft16<1>(g);
        #pragma unroll
        for (int t = 0; t < 16; ++t)
            F[(16 * ka + t) * SS + c] = cmul(g[t], tw[t * ka]);
    }
    __syncthreads();
    invB<SS, 1>(F, tid);      __syncthreads();   // col stepB
    invA<1, SS>(F, tw, tid);  __syncthreads();   // row stepA
    float acc = 0.f;
    invB_mag<1, SS, true>(F, tid, acc);          // row stepB + mag, u1 written
    float ws1 = waveReduceSum(acc);
    if ((tid & 63) == 0) atomicAdd(&coeffs[b * 11 + 1 + j1], ws1 * (1.f / 65536.f));

    int n2 = (3 - j1) * 4;
    if (n2 == 0) return;                         // j1=3: first order only

    __syncthreads();                             // u1 writes visible
    fwdA<1, SS>(F, tw, tid);  __syncthreads();   // rows
    fwdB<1, SS>(F, tid);      __syncthreads();
    fwdA<SS, 1>(F, tw, tid);  __syncthreads();   // cols
    float2 uh[32];
    fwdB_col_capture(F, tid, uh);                // u1_hat in registers only
    // No barrier: the col-stepA below writes exactly the cells this thread
    // just read (same (ka,c) unit mapping).

    const float inv2 = 2.3283064365386963e-10f;  // 1/(16384*16*16384) = 2^-32
    for (int it = 0; it < n2; ++it) {
        int j2 = j1 + 1 + (it >> 2);
        int pair = (j1 == 0) ? (j2 - 1) : ((j1 == 1) ? (j2 + 1) : 5);
        const float* p2 = psi + (size_t)(j2 * 4 + (it & 3)) * NPIX;
        // ---- col stepA: product from uh (registers), fft16, twiddle, one write ----
        #pragma unroll
        for (int i = 0; i < 2; ++i) {
            int u = i * TT + tid;
            int ka = u >> 7, c = u & 127;
            float2 g[16];
            #pragma unroll
            for (int kb = 0; kb < 16; ++kb) {
                float p = p2[(16 * ka + kb) * NN + c];
                float2 z = uh[i * 16 + kb];
                g[kb] = make_float2(z.x * p, z.y * p);
            }
            fft16<1>(g);
            #pragma unroll
            for (int t = 0; t < 16; ++t)
                F[(16 * ka + t) * SS + c] = cmul(g[t], tw[t * ka]);
        }
        __syncthreads();
        invB<SS, 1>(F, tid);      __syncthreads();   // col stepB
        invA<1, SS>(F, tw, tid);  __syncthreads();   // row stepA
        float a2 = 0.f;
        invB_mag<1, SS, false>(F, tid, a2);          // row stepB + register mag sum
        float ws2 = waveReduceSum(a2);
        if ((tid & 63) == 0) atomicAdd(&coeffs[b * 11 + 5 + pair], ws2 * inv2);
        __syncthreads();                             // reads done before next write
    }
}

// ---------- K4: tiny MLP head ----------
__global__ void k_mlp(const float* __restrict__ coeffs,
                      const float* __restrict__ w1, const float* __restrict__ b1,
                      const float* __restrict__ w2, const float* __restrict__ b2,
                      float* __restrict__ out) {
    int b = threadIdx.x;
    if (b >= 64) return;
    float c[11];
    #pragma unroll
    for (int i = 0; i < 11; ++i) c[i] = coeffs[b * 11 + i];
    float h[4];
    #pragma unroll
    for (int k = 0; k < 4; ++k) {
        float s = b1[k];
        #pragma unroll
        for (int i = 0; i < 11; ++i) s += w1[k * 11 + i] * c[i];
        h[k] = fmaxf(s, 0.f);
    }
    #pragma unroll
    for (int o = 0; o < 10; ++o) {
        float s = b2[o];
        #pragma unroll
        for (int k = 0; k < 4; ++k) s += w2[o * 4 + k] * h[k];
        out[b * 10 + o] = 1.f / (1.f + expf(-s));
    }
}

extern "C" void kernel_launch(void* const* d_in, const int* in_sizes, int n_in,
                              void* d_out, int out_size, void* d_ws, size_t ws_size,
                              hipStream_t stream) {
    const float* img = (const float*)d_in[0];
    const float* w1  = (const float*)d_in[1];
    const float* b1  = (const float*)d_in[2];
    const float* w2  = (const float*)d_in[3];
    const float* b2  = (const float*)d_in[4];
    float* out = (float*)d_out;

    // workspace layout (floats): psi[16*16384] | ihat[64*16384 float2] | coeffs[64*11]
    float*  ws     = (float*)d_ws;
    float*  psi    = ws;
    float2* ihat   = (float2*)(ws + 16 * NPIX);
    float*  coeffs = ws + 16 * NPIX + 2 * 64 * NPIX;

    hipLaunchKernelGGL(k_psi,     dim3(17),   dim3(256), 0, stream, psi, coeffs);
    hipLaunchKernelGGL(k_ihat,    dim3(64),   dim3(TT),  0, stream, img, ihat, coeffs);
    hipLaunchKernelGGL(k_scatter, dim3(1024), dim3(TT),  0, stream, ihat, psi, coeffs);
    hipLaunchKernelGGL(k_mlp,     dim3(1),    dim3(64),  0, stream, coeffs, w1, b1, w2, b2, out);
}

// Round 8
// 325.630 us; speedup vs baseline: 2.4666x; 1.3580x over previous
//
#include <hip/hip_runtime.h>
#include <math.h>

#define NN   128
#define SS   129          // LDS row stride in float2 (ODD -> conflict-free lane stride)
#define SG   65           // 64-grid LDS row stride in float2 (65*2 words == 2 mod 32 -> min)
#define TT   512          // R4/R6-proven: ~128 VGPR, no spill, 0 conflicts
#define NPIX 16384        // 128*128
#define EPT  32           // NPIX / TT

__device__ __forceinline__ float2 cmul(float2 a, float2 w) {
    return make_float2(a.x * w.x - a.y * w.y, a.x * w.y + a.y * w.x);
}
__device__ __forceinline__ float2 cmulc(float2 a, float2 w) {   // a * conj(w)
    return make_float2(a.x * w.x + a.y * w.y, a.y * w.x - a.x * w.y);
}

// ---------- register FFT codelets (verified R2-R7) ----------
template<int SGN>
__device__ __forceinline__ void fft8(float2* f) {
    const float R = 0.70710678118654752f;
    const float WC[4] = {1.f, R, 0.f, -R};
    const float WS[4] = {0.f, R, 1.f, R};
    #pragma unroll
    for (int stage = 0; stage < 3; ++stage) {
        const int L = 8 >> stage, half = L >> 1, step = 1 << stage;
        #pragma unroll
        for (int base = 0; base < 8; base += L) {
            #pragma unroll
            for (int j = 0; j < half; ++j) {
                float2 u = f[base + j], v = f[base + half + j];
                f[base + j] = make_float2(u.x + v.x, u.y + v.y);
                float dx = u.x - v.x, dy = u.y - v.y;
                const int t = j * step;
                const float wr = WC[t];
                const float wi = (SGN > 0) ? WS[t] : -WS[t];
                f[base + half + j] = make_float2(dx * wr - dy * wi, dx * wi + dy * wr);
            }
        }
    }
    float2 tmp;
    tmp = f[1]; f[1] = f[4]; f[4] = tmp;
    tmp = f[3]; f[3] = f[6]; f[6] = tmp;
}

template<int SGN>
__device__ __forceinline__ void fft16(float2* f) {
    const float WC[8] = {1.f, 0.92387953251f, 0.70710678119f, 0.38268343236f,
                         0.f, -0.38268343236f, -0.70710678119f, -0.92387953251f};
    const float WS[8] = {0.f, 0.38268343236f, 0.70710678119f, 0.92387953251f,
                         1.f, 0.92387953251f, 0.70710678119f, 0.38268343236f};
    #pragma unroll
    for (int stage = 0; stage < 4; ++stage) {
        const int L = 16 >> stage, half = L >> 1, step = 1 << stage;
        #pragma unroll
        for (int base = 0; base < 16; base += L) {
            #pragma unroll
            for (int j = 0; j < half; ++j) {
                float2 u = f[base + j], v = f[base + half + j];
                f[base + j] = make_float2(u.x + v.x, u.y + v.y);
                float dx = u.x - v.x, dy = u.y - v.y;
                const int t = j * step;
                const float wr = WC[t];
                const float wi = (SGN > 0) ? WS[t] : -WS[t];
                f[base + half + j] = make_float2(dx * wr - dy * wi, dx * wi + dy * wr);
            }
        }
    }
    float2 tmp;
    tmp = f[1];  f[1]  = f[8];  f[8]  = tmp;
    tmp = f[2];  f[2]  = f[4];  f[4]  = tmp;
    tmp = f[3];  f[3]  = f[12]; f[12] = tmp;
    tmp = f[5];  f[5]  = f[10]; f[10] = tmp;
    tmp = f[7];  f[7]  = f[14]; f[14] = tmp;
    tmp = f[11]; f[11] = f[13]; f[13] = tmp;
}

__device__ __forceinline__ float waveReduceSum(float v) {
    #pragma unroll
    for (int off = 32; off > 0; off >>= 1) v += __shfl_down(v, off, 64);
    return v;
}

__device__ __forceinline__ void buildTw(float2* tw, int tid) {
    if (tid < 128) {
        float s, c;
        __sincosf((float)tid * 0.04908738521234052f, &s, &c);   // 2*pi/128
        tw[tid] = make_float2(c, s);
    }
}

// =======================================================================
// 128-grid sweep phases (R6/R7-proven conflict-free lane mappings).
// Per-axis layout: freq k = ka+8*kb stored at position p = 16*ka+kb.
// =======================================================================

template<int ES, int LS>
__device__ __forceinline__ void fwdA(float2* __restrict__ F,
                                     const float2* __restrict__ tw, int tid) {
    #pragma unroll
    for (int i = 0; i < 4; ++i) {
        int u = i * TT + tid;
        int t = u >> 7, x = u & 127;
        float2* M = F + x * LS;
        float2 f[8];
        #pragma unroll
        for (int n1 = 0; n1 < 8; ++n1) f[n1] = M[(t + 16 * n1) * ES];
        fft8<-1>(f);
        #pragma unroll
        for (int ka = 0; ka < 8; ++ka)
            M[(t + 16 * ka) * ES] = cmulc(f[ka], tw[t * ka]);
    }
}

template<int ES, int LS>
__device__ __forceinline__ void fwdB(float2* __restrict__ F, int tid) {
    #pragma unroll
    for (int i = 0; i < 2; ++i) {
        int u = i * TT + tid;
        int ka = u >> 7, x = u & 127;
        float2* M = F + x * LS;
        float2 g[16];
        #pragma unroll
        for (int t = 0; t < 16; ++t) g[t] = M[(16 * ka + t) * ES];
        fft16<-1>(g);
        #pragma unroll
        for (int kb = 0; kb < 16; ++kb) M[(16 * ka + kb) * ES] = g[kb];
    }
}

// Forward column stepB, u1_hat captured straight into registers (no LDS write).
__device__ __forceinline__ void fwdB_col_capture(const float2* __restrict__ F, int tid,
                                                 float2* __restrict__ uh) {
    #pragma unroll
    for (int i = 0; i < 2; ++i) {
        int u = i * TT + tid;
        int ka = u >> 7, c = u & 127;
        float2 g[16];
        #pragma unroll
        for (int t = 0; t < 16; ++t) g[t] = F[(16 * ka + t) * SS + c];
        fft16<-1>(g);
        #pragma unroll
        for (int kb = 0; kb < 16; ++kb) uh[i * 16 + kb] = g[kb];
    }
}

template<int ES, int LS>
__device__ __forceinline__ void invA(float2* __restrict__ F,
                                     const float2* __restrict__ tw, int tid) {
    #pragma unroll
    for (int i = 0; i < 2; ++i) {
        int u = i * TT + tid;
        int ka = u >> 7, x = u & 127;
        float2* M = F + x * LS;
        float2 g[16];
        #pragma unroll
        for (int kb = 0; kb < 16; ++kb) g[kb] = M[(16 * ka + kb) * ES];
        fft16<1>(g);
        #pragma unroll
        for (int t = 0; t < 16; ++t)
            M[(16 * ka + t) * ES] = cmul(g[t], tw[t * ka]);
    }
}

template<int ES, int LS>
__device__ __forceinline__ void invB(float2* __restrict__ F, int tid) {
    #pragma unroll
    for (int i = 0; i < 4; ++i) {
        int u = i * TT + tid;
        int t = u >> 7, x = u & 127;
        float2* M = F + x * LS;
        float2 f[8];
        #pragma unroll
        for (int ka = 0; ka < 8; ++ka) f[ka] = M[(16 * ka + t) * ES];
        fft8<1>(f);
        #pragma unroll
        for (int nh = 0; nh < 8; ++nh) M[(t + 16 * nh) * ES] = f[nh];
    }
}

// Inverse stepB with fused magnitude.
template<int ES, int LS, bool STORE>
__device__ __forceinline__ void invB_mag(float2* __restrict__ F, int tid, float& acc) {
    #pragma unroll
    for (int i = 0; i < 4; ++i) {
        int u = i * TT + tid;
        int t = u >> 7, x = u & 127;
        float2* M = F + x * LS;
        float2 f[8];
        #pragma unroll
        for (int ka = 0; ka < 8; ++ka) f[ka] = M[(16 * ka + t) * ES];
        fft8<1>(f);
        #pragma unroll
        for (int nh = 0; nh < 8; ++nh) {
            float m = sqrtf(f[nh].x * f[nh].x + f[nh].y * f[nh].y);
            if (STORE) {
                m *= (1.f / 16384.f);
                acc += m;
                M[(t + 16 * nh) * ES] = make_float2(m, 0.f);
            } else {
                acc += m;
            }
        }
    }
}

// ---------- K1: Morlet filter bank (permuted freq layout) + zero coeffs ----------
__global__ void k_psi(float* __restrict__ psi, float* __restrict__ coeffs) {
    int blk = blockIdx.x, tid = threadIdx.x;
    if (blk == 16) {
        for (int i = tid; i < 64 * 11; i += 256) coeffs[i] = 0.f;
        return;
    }
    int j = blk >> 2, l = blk & 3;
    float k0    = 2.35619449019234493f / (float)(1 << j);
    float sigma = 0.8f * (float)(1 << j);
    float s2    = sigma * sigma;
    float theta = 0.78539816339744831f * (float)l;
    float k0x = k0 * cosf(theta);
    float k0y = k0 * sinf(theta);
    float beta = expf(-0.5f * s2 * k0 * k0);
    const float FSTEP = 0.04908738521234052f;
    float* dst = psi + (size_t)blk * NPIX;
    for (int i = tid; i < NPIX; i += 256) {
        int pr = i >> 7, pc = i & 127;
        int kr = (pr >> 4) + 8 * (pr & 15);
        int kc = (pc >> 4) + 8 * (pc & 15);
        float fr = (float)(kr < 64 ? kr : kr - 128) * FSTEP;
        float fc = (float)(kc < 64 ? kc : kc - 128) * FSTEP;
        float dx = fr - k0x, dy = fc - k0y;
        float g1 = expf(-0.5f * s2 * (dx * dx + dy * dy));
        float g0 = expf(-0.5f * s2 * (fr * fr + fc * fc));
        dst[i] = g1 - beta * g0;
    }
}

// ---------- K2: i_hat = fft2(image) (permuted layout), s0 ----------
__global__ __attribute__((amdgpu_flat_work_group_size(TT, TT), amdgpu_waves_per_eu(2, 2)))
void k_ihat(const float* __restrict__ img,
            float2* __restrict__ ihat,
            float* __restrict__ coeffs) {
    __shared__ float2 F[NN * SS];
    __shared__ float2 tw[128];
    int tid = threadIdx.x, b = blockIdx.x;
    buildTw(tw, tid);
    const float* im = img + (size_t)b * NPIX;
    float acc = 0.f;
    #pragma unroll
    for (int k = 0; k < EPT; ++k) {
        int e = k * TT + tid;
        float v = im[e];
        acc += v;
        F[(e >> 7) * SS + (e & 127)] = make_float2(v, 0.f);
    }
    float ws = waveReduceSum(acc);
    if ((tid & 63) == 0) atomicAdd(&coeffs[b * 11 + 0], ws * (1.f / 16384.f));
    __syncthreads();
    fwdA<1, SS>(F, tw, tid);  __syncthreads();
    fwdB<1, SS>(F, tid);      __syncthreads();
    fwdA<SS, 1>(F, tw, tid);  __syncthreads();
    float2 uh[32];
    fwdB_col_capture(F, tid, uh);
    float2* dst = ihat + (size_t)b * NPIX;
    #pragma unroll
    for (int i = 0; i < 2; ++i) {
        int u = i * TT + tid;
        int ka = u >> 7, c = u & 127;
        #pragma unroll
        for (int kb = 0; kb < 16; ++kb)
            dst[(16 * ka + kb) * NN + c] = uh[i * 16 + kb];
    }
}

// ---------- K3: fused first+second order scattering per (b, j1, l1) ----------
__global__ __attribute__((amdgpu_flat_work_group_size(TT, TT), amdgpu_waves_per_eu(2, 2)))
void k_scatter(const float2* __restrict__ ihat,
               const float* __restrict__ psi,
               float* __restrict__ coeffs) {
    __shared__ float2 F[NN * SS];
    __shared__ float2 tw[128];
    int tid = threadIdx.x;
    int x = blockIdx.x;
    int b = x & 63, l1 = (x >> 6) & 3, j1 = x >> 8;
    const float2* ih = ihat + (size_t)b * NPIX;
    const float*  p1 = psi + (size_t)(j1 * 4 + l1) * NPIX;
    buildTw(tw, tid);

    // ---- first inverse, COLUMN pass stepA from the global product (registers) ----
    #pragma unroll
    for (int i = 0; i < 2; ++i) {
        int u = i * TT + tid;
        int ka = u >> 7, c = u & 127;
        float2 g[16];
        #pragma unroll
        for (int kb = 0; kb < 16; ++kb) {
            int e = (16 * ka + kb) * NN + c;
            float2 z = ih[e];
            float  p = p1[e];
            g[kb] = make_float2(z.x * p, z.y * p);
        }
        fft16<1>(g);
        #pragma unroll
        for (int t = 0; t < 16; ++t)
            F[(16 * ka + t) * SS + c] = cmul(g[t], tw[t * ka]);
    }
    __syncthreads();
    invB<SS, 1>(F, tid);      __syncthreads();
    invA<1, SS>(F, tw, tid);  __syncthreads();
    float acc = 0.f;
    invB_mag<1, SS, true>(F, tid, acc);          // u1 written at spatial cells
    float ws1 = waveReduceSum(acc);
    if ((tid & 63) == 0) atomicAdd(&coeffs[b * 11 + 1 + j1], ws1 * (1.f / 65536.f));

    int n2 = (3 - j1) * 4;
    if (n2 == 0) return;                         // j1=3: first order only

    __syncthreads();                             // u1 writes visible
    fwdA<1, SS>(F, tw, tid);  __syncthreads();
    fwdB<1, SS>(F, tid);      __syncthreads();
    fwdA<SS, 1>(F, tw, tid);  __syncthreads();
    float2 uh[32];
    fwdB_col_capture(F, tid, uh);                // u1_hat in registers only
    // No barrier: writes below hit exactly the cells this thread just read.

    int kalo = tid >> 7, c = tid & 127;          // (i -> ka = kalo+4*i), column c
    int m = c & 15;
    bool colKeep = (m < 4) || (m >= 12);         // column freq kc in [-32..31]
    int pc64 = 8 * (c >> 4) + ((m < 4) ? m : (m - 8));   // perm64 col position

    const float inv2   = 2.3283064365386963e-10f; // 1/(16384*16*128^2)
    const float inv64  = 9.3132257461547852e-10f; // 1/(16384*16*64^2)

    for (int it = 0; it < n2; ++it) {
        int j2 = j1 + 1 + (it >> 2);
        int pair = (j1 == 0) ? (j2 - 1) : ((j1 == 1) ? (j2 + 1) : 5);
        const float* p2 = psi + (size_t)(j2 * 4 + (it & 3)) * NPIX;

        if (j2 == 1) {
            // ================= FULL 128-grid iteration (j1=0, j2=1 only) =========
            #pragma unroll
            for (int i = 0; i < 2; ++i) {
                int ka = kalo + 4 * i;
                float2 g[16];
                #pragma unroll
                for (int kb = 0; kb < 16; ++kb) {
                    float p = p2[(16 * ka + kb) * NN + c];
                    float2 z = uh[i * 16 + kb];
                    g[kb] = make_float2(z.x * p, z.y * p);
                }
                fft16<1>(g);
                #pragma unroll
                for (int t = 0; t < 16; ++t)
                    F[(16 * ka + t) * SS + c] = cmul(g[t], tw[t * ka]);
            }
            __syncthreads();
            invB<SS, 1>(F, tid);      __syncthreads();
            invA<1, SS>(F, tw, tid);  __syncthreads();
            float a2 = 0.f;
            invB_mag<1, SS, false>(F, tid, a2);
            float ws2 = waveReduceSum(a2);
            if ((tid & 63) == 0) atomicAdd(&coeffs[b * 11 + 5 + pair], ws2 * inv2);
            __syncthreads();
        } else {
            // ================= TRUNCATED 64-grid iteration (j2 >= 2) =============
            // psi_{j2>=2} lives inside the central +-32-bin box (worst case j2=2:
            // boundary at 3.1 sigma, tail <= 0.8%).  Gather the central 64x64 freq
            // block of uh*psi2 into G (aliases F), inverse-DFT on the 64 grid
            // (= field sampled on the stride-2 spatial subgrid), mean |.| there.
            float2* G = F;       // 64*SG*8B = 33 KB, F is dead during trunc iters
            if (colKeep) {
                #pragma unroll
                for (int i = 0; i < 2; ++i) {
                    int ka = kalo + 4 * i;
                    #pragma unroll
                    for (int kb = 0; kb < 16; ++kb) {
                        if (kb < 4 || kb >= 12) {
                            // full-grid row pos 16ka+kb <-> kr = ka+8kb;
                            // perm64 row pos = 8*ka + (kb or kb-8)
                            float p = p2[(16 * ka + kb) * NN + c];
                            float2 z = uh[i * 16 + kb];
                            int pr64 = 8 * ka + ((kb < 4) ? kb : (kb - 8));
                            G[pr64 * SG + pc64] = make_float2(z.x * p, z.y * p);
                        }
                    }
                }
            }
            __syncthreads();
            // ---- column-axis pass (64 = 8x8: k = ka+8kb at pos 8ka+kb) ----
            {   // stepA: fft8 over kb per class ka; twiddle w64^{n2*ka}
                int col = tid & 63, ka = tid >> 6;
                float2 f[8];
                #pragma unroll
                for (int kb = 0; kb < 8; ++kb) f[kb] = G[(8 * ka + kb) * SG + col];
                fft8<1>(f);
                #pragma unroll
                for (int q = 0; q < 8; ++q)
                    G[(8 * ka + q) * SG + col] = cmul(f[q], tw[2 * q * ka]);
            }
            __syncthreads();
            {   // stepB: fft8 over ka per class n2 -> spatial rows (natural order)
                int col = tid & 63, q = tid >> 6;
                float2 f[8];
                #pragma unroll
                for (int ka = 0; ka < 8; ++ka) f[ka] = G[(8 * ka + q) * SG + col];
                fft8<1>(f);
                #pragma unroll
                for (int n1 = 0; n1 < 8; ++n1) G[(8 * n1 + q) * SG + col] = f[n1];
            }
            __syncthreads();
            // ---- row-axis pass ----
            {   // stepA
                int row = tid & 63, ka = tid >> 6;
                float2* R = G + row * SG + 8 * ka;
                float2 f[8];
                #pragma unroll
                for (int kb = 0; kb < 8; ++kb) f[kb] = R[kb];
                fft8<1>(f);
                #pragma unroll
                for (int q = 0; q < 8; ++q) R[q] = cmul(f[q], tw[2 * q * ka]);
            }
            __syncthreads();
            // stepB + fused magnitude (register-only, no store)
            float a2 = 0.f;
            {
                int row = tid & 63, q = tid >> 6;
                float2* R = G + row * SG + q;
                float2 f[8];
                #pragma unroll
                for (int ka = 0; ka < 8; ++ka) f[ka] = R[8 * ka];
                fft8<1>(f);
                #pragma unroll
                for (int n1 = 0; n1 < 8; ++n1)
                    a2 += sqrtf(f[n1].x * f[n1].x + f[n1].y * f[n1].y);
            }
            float ws2 = waveReduceSum(a2);
            if ((tid & 63) == 0) atomicAdd(&coeffs[b * 11 + 5 + pair], ws2 * inv64);
            __syncthreads();
        }
    }
}

// ---------- K4: tiny MLP head ----------
__global__ void k_mlp(const float* __restrict__ coeffs,
                      const float* __restrict__ w1, const float* __restrict__ b1,
                      const float* __restrict__ w2, const float* __restrict__ b2,
                      float* __restrict__ out) {
    int b = threadIdx.x;
    if (b >= 64) return;
    float c[11];
    #pragma unroll
    for (int i = 0; i < 11; ++i) c[i] = coeffs[b * 11 + i];
    float h[4];
    #pragma unroll
    for (int k = 0; k < 4; ++k) {
        float s = b1[k];
        #pragma unroll
        for (int i = 0; i < 11; ++i) s += w1[k * 11 + i] * c[i];
        h[k] = fmaxf(s, 0.f);
    }
    #pragma unroll
    for (int o = 0; o < 10; ++o) {
        float s = b2[o];
        #pragma unroll
        for (int k = 0; k < 4; ++k) s += w2[o * 4 + k] * h[k];
        out[b * 10 + o] = 1.f / (1.f + expf(-s));
    }
}

extern "C" void kernel_launch(void* const* d_in, const int* in_sizes, int n_in,
                              void* d_out, int out_size, void* d_ws, size_t ws_size,
                              hipStream_t stream) {
    const float* img = (const float*)d_in[0];
    const float* w1  = (const float*)d_in[1];
    const float* b1  = (const float*)d_in[2];
    const float* w2  = (const float*)d_in[3];
    const float* b2  = (const float*)d_in[4];
    float* out = (float*)d_out;

    // workspace layout (floats): psi[16*16384] | ihat[64*16384 float2] | coeffs[64*11]
    float*  ws     = (float*)d_ws;
    float*  psi    = ws;
    float2* ihat   = (float2*)(ws + 16 * NPIX);
    float*  coeffs = ws + 16 * NPIX + 2 * 64 * NPIX;

    hipLaunchKernelGGL(k_psi,     dim3(17),   dim3(256), 0, stream, psi, coeffs);
    hipLaunchKernelGGL(k_ihat,    dim3(64),   dim3(TT),  0, stream, img, ihat, coeffs);
    hipLaunchKernelGGL(k_scatter, dim3(1024), dim3(TT),  0, stream, ihat, psi, coeffs);
    hipLaunchKernelGGL(k_mlp,     dim3(1),    dim3(64),  0, stream, coeffs, w1, b1, w2, b2, out);
}

// Round 9
// 286.928 us; speedup vs baseline: 2.7993x; 1.1349x over previous
//
#include <hip/hip_runtime.h>
#include <math.h>

#define NN   128
#define SS   129          // LDS row stride in float2 (ODD -> conflict-free lane stride)
#define TT   512          // R4/R6-proven: ~128 VGPR, no spill, 0 conflicts
#define NPIX 16384        // 128*128
#define EPT  32           // NPIX / TT

__device__ __forceinline__ float2 cmul(float2 a, float2 w) {
    return make_float2(a.x * w.x - a.y * w.y, a.x * w.y + a.y * w.x);
}
__device__ __forceinline__ float2 cmulc(float2 a, float2 w) {   // a * conj(w)
    return make_float2(a.x * w.x + a.y * w.y, a.y * w.x - a.x * w.y);
}

// ---------- register FFT codelets (verified R2-R8) ----------
template<int SGN>
__device__ __forceinline__ void fft8(float2* f) {
    const float R = 0.70710678118654752f;
    const float WC[4] = {1.f, R, 0.f, -R};
    const float WS[4] = {0.f, R, 1.f, R};
    #pragma unroll
    for (int stage = 0; stage < 3; ++stage) {
        const int L = 8 >> stage, half = L >> 1, step = 1 << stage;
        #pragma unroll
        for (int base = 0; base < 8; base += L) {
            #pragma unroll
            for (int j = 0; j < half; ++j) {
                float2 u = f[base + j], v = f[base + half + j];
                f[base + j] = make_float2(u.x + v.x, u.y + v.y);
                float dx = u.x - v.x, dy = u.y - v.y;
                const int t = j * step;
                const float wr = WC[t];
                const float wi = (SGN > 0) ? WS[t] : -WS[t];
                f[base + half + j] = make_float2(dx * wr - dy * wi, dx * wi + dy * wr);
            }
        }
    }
    float2 tmp;
    tmp = f[1]; f[1] = f[4]; f[4] = tmp;
    tmp = f[3]; f[3] = f[6]; f[6] = tmp;
}

template<int SGN>
__device__ __forceinline__ void fft16(float2* f) {
    const float WC[8] = {1.f, 0.92387953251f, 0.70710678119f, 0.38268343236f,
                         0.f, -0.38268343236f, -0.70710678119f, -0.92387953251f};
    const float WS[8] = {0.f, 0.38268343236f, 0.70710678119f, 0.92387953251f,
                         1.f, 0.92387953251f, 0.70710678119f, 0.38268343236f};
    #pragma unroll
    for (int stage = 0; stage < 4; ++stage) {
        const int L = 16 >> stage, half = L >> 1, step = 1 << stage;
        #pragma unroll
        for (int base = 0; base < 16; base += L) {
            #pragma unroll
            for (int j = 0; j < half; ++j) {
                float2 u = f[base + j], v = f[base + half + j];
                f[base + j] = make_float2(u.x + v.x, u.y + v.y);
                float dx = u.x - v.x, dy = u.y - v.y;
                const int t = j * step;
                const float wr = WC[t];
                const float wi = (SGN > 0) ? WS[t] : -WS[t];
                f[base + half + j] = make_float2(dx * wr - dy * wi, dx * wi + dy * wr);
            }
        }
    }
    float2 tmp;
    tmp = f[1];  f[1]  = f[8];  f[8]  = tmp;
    tmp = f[2];  f[2]  = f[4];  f[4]  = tmp;
    tmp = f[3];  f[3]  = f[12]; f[12] = tmp;
    tmp = f[5];  f[5]  = f[10]; f[10] = tmp;
    tmp = f[7];  f[7]  = f[14]; f[14] = tmp;
    tmp = f[11]; f[11] = f[13]; f[13] = tmp;
}

__device__ __forceinline__ float waveReduceSum(float v) {
    #pragma unroll
    for (int off = 32; off > 0; off >>= 1) v += __shfl_down(v, off, 64);
    return v;
}

__device__ __forceinline__ void buildTw(float2* tw, int tid) {
    if (tid < 128) {
        float s, c;
        __sincosf((float)tid * 0.04908738521234052f, &s, &c);   // 2*pi/128
        tw[tid] = make_float2(c, s);
    }
}

// ======== 128-grid sweep phases (R6/R7-proven conflict-free mappings) ========
// Per-axis layout: freq k = ka+8*kb stored at position p = 16*ka+kb.

template<int ES, int LS>
__device__ __forceinline__ void fwdA(float2* __restrict__ F,
                                     const float2* __restrict__ tw, int tid) {
    #pragma unroll
    for (int i = 0; i < 4; ++i) {
        int u = i * TT + tid;
        int t = u >> 7, x = u & 127;
        float2* M = F + x * LS;
        float2 f[8];
        #pragma unroll
        for (int n1 = 0; n1 < 8; ++n1) f[n1] = M[(t + 16 * n1) * ES];
        fft8<-1>(f);
        #pragma unroll
        for (int ka = 0; ka < 8; ++ka)
            M[(t + 16 * ka) * ES] = cmulc(f[ka], tw[t * ka]);
    }
}

template<int ES, int LS>
__device__ __forceinline__ void fwdB(float2* __restrict__ F, int tid) {
    #pragma unroll
    for (int i = 0; i < 2; ++i) {
        int u = i * TT + tid;
        int ka = u >> 7, x = u & 127;
        float2* M = F + x * LS;
        float2 g[16];
        #pragma unroll
        for (int t = 0; t < 16; ++t) g[t] = M[(16 * ka + t) * ES];
        fft16<-1>(g);
        #pragma unroll
        for (int kb = 0; kb < 16; ++kb) M[(16 * ka + kb) * ES] = g[kb];
    }
}

__device__ __forceinline__ void fwdB_col_capture(const float2* __restrict__ F, int tid,
                                                 float2* __restrict__ uh) {
    #pragma unroll
    for (int i = 0; i < 2; ++i) {
        int u = i * TT + tid;
        int ka = u >> 7, c = u & 127;
        float2 g[16];
        #pragma unroll
        for (int t = 0; t < 16; ++t) g[t] = F[(16 * ka + t) * SS + c];
        fft16<-1>(g);
        #pragma unroll
        for (int kb = 0; kb < 16; ++kb) uh[i * 16 + kb] = g[kb];
    }
}

template<int ES, int LS>
__device__ __forceinline__ void invA(float2* __restrict__ F,
                                     const float2* __restrict__ tw, int tid) {
    #pragma unroll
    for (int i = 0; i < 2; ++i) {
        int u = i * TT + tid;
        int ka = u >> 7, x = u & 127;
        float2* M = F + x * LS;
        float2 g[16];
        #pragma unroll
        for (int kb = 0; kb < 16; ++kb) g[kb] = M[(16 * ka + kb) * ES];
        fft16<1>(g);
        #pragma unroll
        for (int t = 0; t < 16; ++t)
            M[(16 * ka + t) * ES] = cmul(g[t], tw[t * ka]);
    }
}

template<int ES, int LS>
__device__ __forceinline__ void invB(float2* __restrict__ F, int tid) {
    #pragma unroll
    for (int i = 0; i < 4; ++i) {
        int u = i * TT + tid;
        int t = u >> 7, x = u & 127;
        float2* M = F + x * LS;
        float2 f[8];
        #pragma unroll
        for (int ka = 0; ka < 8; ++ka) f[ka] = M[(16 * ka + t) * ES];
        fft8<1>(f);
        #pragma unroll
        for (int nh = 0; nh < 8; ++nh) M[(t + 16 * nh) * ES] = f[nh];
    }
}

template<int ES, int LS, bool STORE>
__device__ __forceinline__ void invB_mag(float2* __restrict__ F, int tid, float& acc) {
    #pragma unroll
    for (int i = 0; i < 4; ++i) {
        int u = i * TT + tid;
        int t = u >> 7, x = u & 127;
        float2* M = F + x * LS;
        float2 f[8];
        #pragma unroll
        for (int ka = 0; ka < 8; ++ka) f[ka] = M[(16 * ka + t) * ES];
        fft8<1>(f);
        #pragma unroll
        for (int nh = 0; nh < 8; ++nh) {
            float m = sqrtf(f[nh].x * f[nh].x + f[nh].y * f[nh].y);
            if (STORE) {
                m *= (1.f / 16384.f);
                acc += m;
                M[(t + 16 * nh) * ES] = make_float2(m, 0.f);
            } else {
                acc += m;
            }
        }
    }
}

// ---------- K1: Morlet filter bank (permuted freq layout) + zero coeffs ----------
__global__ void k_psi(float* __restrict__ psi, float* __restrict__ coeffs) {
    int blk = blockIdx.x, tid = threadIdx.x;
    if (blk == 16) {
        for (int i = tid; i < 64 * 11; i += 256) coeffs[i] = 0.f;
        return;
    }
    int j = blk >> 2, l = blk & 3;
    float k0    = 2.35619449019234493f / (float)(1 << j);
    float sigma = 0.8f * (float)(1 << j);
    float s2    = sigma * sigma;
    float theta = 0.78539816339744831f * (float)l;
    float k0x = k0 * cosf(theta);
    float k0y = k0 * sinf(theta);
    float beta = expf(-0.5f * s2 * k0 * k0);
    const float FSTEP = 0.04908738521234052f;
    float* dst = psi + (size_t)blk * NPIX;
    for (int i = tid; i < NPIX; i += 256) {
        int pr = i >> 7, pc = i & 127;
        int kr = (pr >> 4) + 8 * (pr & 15);
        int kc = (pc >> 4) + 8 * (pc & 15);
        float fr = (float)(kr < 64 ? kr : kr - 128) * FSTEP;
        float fc = (float)(kc < 64 ? kc : kc - 128) * FSTEP;
        float dx = fr - k0x, dy = fc - k0y;
        float g1 = expf(-0.5f * s2 * (dx * dx + dy * dy));
        float g0 = expf(-0.5f * s2 * (fr * fr + fc * fc));
        dst[i] = g1 - beta * g0;
    }
}

// ---------- K2: i_hat = fft2(image) (permuted layout), s0 ----------
__global__ __attribute__((amdgpu_flat_work_group_size(TT, TT), amdgpu_waves_per_eu(2, 2)))
void k_ihat(const float* __restrict__ img,
            float2* __restrict__ ihat,
            float* __restrict__ coeffs) {
    __shared__ float2 F[NN * SS];
    __shared__ float2 tw[128];
    int tid = threadIdx.x, b = blockIdx.x;
    buildTw(tw, tid);
    const float* im = img + (size_t)b * NPIX;
    float acc = 0.f;
    #pragma unroll
    for (int k = 0; k < EPT; ++k) {
        int e = k * TT + tid;
        float v = im[e];
        acc += v;
        F[(e >> 7) * SS + (e & 127)] = make_float2(v, 0.f);
    }
    float ws = waveReduceSum(acc);
    if ((tid & 63) == 0) atomicAdd(&coeffs[b * 11 + 0], ws * (1.f / 16384.f));
    __syncthreads();
    fwdA<1, SS>(F, tw, tid);  __syncthreads();
    fwdB<1, SS>(F, tid);      __syncthreads();
    fwdA<SS, 1>(F, tw, tid);  __syncthreads();
    float2 uh[32];
    fwdB_col_capture(F, tid, uh);
    float2* dst = ihat + (size_t)b * NPIX;
    #pragma unroll
    for (int i = 0; i < 2; ++i) {
        int u = i * TT + tid;
        int ka = u >> 7, c = u & 127;
        #pragma unroll
        for (int kb = 0; kb < 16; ++kb)
            dst[(16 * ka + kb) * NN + c] = uh[i * 16 + kb];
    }
}

// ---------- K3: fused first+second order scattering per (b, j1, l1) ----------
__global__ __attribute__((amdgpu_flat_work_group_size(TT, TT), amdgpu_waves_per_eu(2, 2)))
void k_scatter(const float2* __restrict__ ihat,
               const float* __restrict__ psi,
               float* __restrict__ coeffs) {
    __shared__ __align__(16) float2 F[NN * SS];
    __shared__ float2 tw[128];
    // Aliased sub-buffers for the truncated path (F is dead then):
    //  G4 = float4[64*65]  (two 64x64 sub-grids packed x,y / z,w)  = floats 0..16639
    //  H  = float2[64*64]  (central block of u1_hat, perm64 layout) = F[8320..12415]
    float4* G4 = (float4*)F;
    float2* H  = F + 8320;
    int tid = threadIdx.x;
    int x = blockIdx.x;
    int b = x & 63, l1 = (x >> 6) & 3, j1 = x >> 8;
    const float2* ih = ihat + (size_t)b * NPIX;
    const float*  p1 = psi + (size_t)(j1 * 4 + l1) * NPIX;
    buildTw(tw, tid);

    // ---- first inverse, COLUMN pass stepA from the global product (registers) ----
    #pragma unroll
    for (int i = 0; i < 2; ++i) {
        int u = i * TT + tid;
        int ka = u >> 7, c = u & 127;
        float2 g[16];
        #pragma unroll
        for (int kb = 0; kb < 16; ++kb) {
            int e = (16 * ka + kb) * NN + c;
            float2 z = ih[e];
            float  p = p1[e];
            g[kb] = make_float2(z.x * p, z.y * p);
        }
        fft16<1>(g);
        #pragma unroll
        for (int t = 0; t < 16; ++t)
            F[(16 * ka + t) * SS + c] = cmul(g[t], tw[t * ka]);
    }
    __syncthreads();
    invB<SS, 1>(F, tid);      __syncthreads();
    invA<1, SS>(F, tw, tid);  __syncthreads();
    float acc = 0.f;
    invB_mag<1, SS, true>(F, tid, acc);          // u1 written at spatial cells
    float ws1 = waveReduceSum(acc);
    if ((tid & 63) == 0) atomicAdd(&coeffs[b * 11 + 1 + j1], ws1 * (1.f / 65536.f));
    if (j1 == 3) return;                          // first order only

    __syncthreads();                              // u1 writes visible
    fwdA<1, SS>(F, tw, tid);  __syncthreads();
    fwdB<1, SS>(F, tid);      __syncthreads();
    fwdA<SS, 1>(F, tw, tid);  __syncthreads();
    float2 uh[32];
    fwdB_col_capture(F, tid, uh);                 // u1_hat in registers

    int kalo = tid >> 7, c = tid & 127;
    int m = c & 15;
    bool colKeep = (m < 4) || (m >= 12);          // column freq kc in [-32..31]
    int pc64 = 8 * (c >> 4) + ((m < 4) ? m : (m - 8));

    const float inv2  = 2.3283064365386963e-10f;  // 1/(16384*16*128^2)
    const float inv64 = 9.3132257461547852e-10f;  // 1/(16384*16*64^2)

    // ====== FULL 128-grid iterations: only j2 == 1 (i.e. j1 == 0), pair 0 ======
    if (j1 == 0) {
        for (int it = 0; it < 4; ++it) {
            const float* p2 = psi + (size_t)(4 + it) * NPIX;
            #pragma unroll
            for (int i = 0; i < 2; ++i) {
                int ka = kalo + 4 * i;
                float2 g[16];
                #pragma unroll
                for (int kb = 0; kb < 16; ++kb) {
                    float p = p2[(16 * ka + kb) * NN + c];
                    float2 z = uh[i * 16 + kb];
                    g[kb] = make_float2(z.x * p, z.y * p);
                }
                fft16<1>(g);
                #pragma unroll
                for (int t = 0; t < 16; ++t)
                    F[(16 * ka + t) * SS + c] = cmul(g[t], tw[t * ka]);
            }
            __syncthreads();
            invB<SS, 1>(F, tid);      __syncthreads();
            invA<1, SS>(F, tw, tid);  __syncthreads();
            float a2 = 0.f;
            invB_mag<1, SS, false>(F, tid, a2);
            float ws2 = waveReduceSum(a2);
            if ((tid & 63) == 0) atomicAdd(&coeffs[b * 11 + 5 + 0], ws2 * inv2);
            __syncthreads();
        }
    } else {
        __syncthreads();   // capture reads of F complete before H writes below
    }

    // ====== Park central 64x64 of u1_hat in LDS; uh registers die here ======
    if (colKeep) {
        #pragma unroll
        for (int i = 0; i < 2; ++i) {
            int ka = kalo + 4 * i;
            #pragma unroll
            for (int kb = 0; kb < 16; ++kb) {
                if (kb < 4 || kb >= 12) {
                    int pr64 = 8 * ka + ((kb < 4) ? kb : (kb - 8));
                    H[pr64 * 64 + pc64] = uh[i * 16 + kb];
                }
            }
        }
    }
    __syncthreads();

    // ====== TRUNCATED 64-grid groups: j2 >= 2, two filters per sweep set ======
    // psi_{j2>=2} lives inside the central +-32-bin box (worst case j2=2: 3.1
    // sigma, tail <= 0.8%).  Sub-sampled spatial mean is exact quadrature for
    // the band-limited field.  Two filters packed in float4 (x,y | z,w).
    for (int j2 = (j1 >= 1 ? j1 + 1 : 2); j2 <= 3; ++j2) {
        int pair = (j1 == 0) ? (j2 - 1) : ((j1 == 1) ? (j2 + 1) : 5);
        for (int half = 0; half < 2; ++half) {
            const float* p2a = psi + (size_t)(j2 * 4 + 2 * half) * NPIX;
            const float* p2b = p2a + NPIX;
            if (colKeep) {
                #pragma unroll
                for (int i = 0; i < 2; ++i) {
                    int ka = kalo + 4 * i;
                    #pragma unroll
                    for (int kb = 0; kb < 16; ++kb) {
                        if (kb < 4 || kb >= 12) {
                            int pr64 = 8 * ka + ((kb < 4) ? kb : (kb - 8));
                            float2 z = H[pr64 * 64 + pc64];
                            int e = (16 * ka + kb) * NN + c;
                            float pa = p2a[e], pb = p2b[e];
                            G4[pr64 * 65 + pc64] =
                                make_float4(z.x * pa, z.y * pa, z.x * pb, z.y * pb);
                        }
                    }
                }
            }
            __syncthreads();
            // ---- column-axis pass (64 = 8x8: k = ka+8kb at pos 8ka+kb) ----
            {   // stepA: fft8 over kb per ka; twiddle w64^{q*ka}
                int col = tid & 63, ka = tid >> 6;
                float2 f0[8], f1[8];
                #pragma unroll
                for (int kb = 0; kb < 8; ++kb) {
                    float4 v = G4[(8 * ka + kb) * 65 + col];
                    f0[kb] = make_float2(v.x, v.y); f1[kb] = make_float2(v.z, v.w);
                }
                fft8<1>(f0); fft8<1>(f1);
                #pragma unroll
                for (int q = 0; q < 8; ++q) {
                    float2 w = tw[2 * q * ka];
                    float2 a = cmul(f0[q], w), d = cmul(f1[q], w);
                    G4[(8 * ka + q) * 65 + col] = make_float4(a.x, a.y, d.x, d.y);
                }
            }
            __syncthreads();
            {   // stepB: fft8 over ka per class q -> spatial rows
                int col = tid & 63, q = tid >> 6;
                float2 f0[8], f1[8];
                #pragma unroll
                for (int ka = 0; ka < 8; ++ka) {
                    float4 v = G4[(8 * ka + q) * 65 + col];
                    f0[ka] = make_float2(v.x, v.y); f1[ka] = make_float2(v.z, v.w);
                }
                fft8<1>(f0); fft8<1>(f1);
                #pragma unroll
                for (int n1 = 0; n1 < 8; ++n1)
                    G4[(8 * n1 + q) * 65 + col] =
                        make_float4(f0[n1].x, f0[n1].y, f1[n1].x, f1[n1].y);
            }
            __syncthreads();
            // ---- row-axis pass ----
            {   // stepA
                int row = tid & 63, ka = tid >> 6;
                float4* R = G4 + row * 65 + 8 * ka;
                float2 f0[8], f1[8];
                #pragma unroll
                for (int kb = 0; kb < 8; ++kb) {
                    float4 v = R[kb];
                    f0[kb] = make_float2(v.x, v.y); f1[kb] = make_float2(v.z, v.w);
                }
                fft8<1>(f0); fft8<1>(f1);
                #pragma unroll
                for (int q = 0; q < 8; ++q) {
                    float2 w = tw[2 * q * ka];
                    float2 a = cmul(f0[q], w), d = cmul(f1[q], w);
                    R[q] = make_float4(a.x, a.y, d.x, d.y);
                }
            }
            __syncthreads();
            // stepB + fused magnitude (both filters -> same pair coefficient)
            float a2 = 0.f;
            {
                int row = tid & 63, q = tid >> 6;
                float4* R = G4 + row * 65 + q;
                float2 f0[8], f1[8];
                #pragma unroll
                for (int ka = 0; ka < 8; ++ka) {
                    float4 v = R[8 * ka];
                    f0[ka] = make_float2(v.x, v.y); f1[ka] = make_float2(v.z, v.w);
                }
                fft8<1>(f0); fft8<1>(f1);
                #pragma unroll
                for (int n1 = 0; n1 < 8; ++n1) {
                    a2 += sqrtf(f0[n1].x * f0[n1].x + f0[n1].y * f0[n1].y);
                    a2 += sqrtf(f1[n1].x * f1[n1].x + f1[n1].y * f1[n1].y);
                }
            }
            float ws2 = waveReduceSum(a2);
            if ((tid & 63) == 0) atomicAdd(&coeffs[b * 11 + 5 + pair], ws2 * inv64);
            __syncthreads();   // G4 reads done before next gather overwrites
        }
    }
}

// ---------- K4: tiny MLP head ----------
__global__ void k_mlp(const float* __restrict__ coeffs,
                      const float* __restrict__ w1, const float* __restrict__ b1,
                      const float* __restrict__ w2, const float* __restrict__ b2,
                      float* __restrict__ out) {
    int b = threadIdx.x;
    if (b >= 64) return;
    float c[11];
    #pragma unroll
    for (int i = 0; i < 11; ++i) c[i] = coeffs[b * 11 + i];
    float h[4];
    #pragma unroll
    for (int k = 0; k < 4; ++k) {
        float s = b1[k];
        #pragma unroll
        for (int i = 0; i < 11; ++i) s += w1[k * 11 + i] * c[i];
        h[k] = fmaxf(s, 0.f);
    }
    #pragma unroll
    for (int o = 0; o < 10; ++o) {
        float s = b2[o];
        #pragma unroll
        for (int k = 0; k < 4; ++k) s += w2[o * 4 + k] * h[k];
        out[b * 10 + o] = 1.f / (1.f + expf(-s));
    }
}

extern "C" void kernel_launch(void* const* d_in, const int* in_sizes, int n_in,
                              void* d_out, int out_size, void* d_ws, size_t ws_size,
                              hipStream_t stream) {
    const float* img = (const float*)d_in[0];
    const float* w1  = (const float*)d_in[1];
    const float* b1  = (const float*)d_in[2];
    const float* w2  = (const float*)d_in[3];
    const float* b2  = (const float*)d_in[4];
    float* out = (float*)d_out;

    // workspace layout (floats): psi[16*16384] | ihat[64*16384 float2] | coeffs[64*11]
    float*  ws     = (float*)d_ws;
    float*  psi    = ws;
    float2* ihat   = (float2*)(ws + 16 * NPIX);
    float*  coeffs = ws + 16 * NPIX + 2 * 64 * NPIX;

    hipLaunchKernelGGL(k_psi,     dim3(17),   dim3(256), 0, stream, psi, coeffs);
    hipLaunchKernelGGL(k_ihat,    dim3(64),   dim3(TT),  0, stream, img, ihat, coeffs);
    hipLaunchKernelGGL(k_scatter, dim3(1024), dim3(TT),  0, stream, ihat, psi, coeffs);
    hipLaunchKernelGGL(k_mlp,     dim3(1),    dim3(64),  0, stream, coeffs, w1, b1, w2, b2, out);
}